// Round 13
// baseline (638.658 us; speedup 1.0000x reference)
//
#include <hip/hip_runtime.h>
#include <math.h>

#define NUSERS 50000
#define NITEMS 50000
#define NTOT   100000
#define NNODE  50000      // per direction
#define MTILES 6250       // 100000/16 row tiles
#define KDIM   384        // folded K: [mean_src 128 | tenc 64 | ef 64 | h 128]
#define NWAVES 8192       // gather: 2048 blocks x 4 waves, grid-stride over nodes
#define PBLK   768        // prep: pack_w blocks (512*384/256)
#define CBLK   6250       // prep: cast_mem blocks

typedef __attribute__((ext_vector_type(4))) float f32x4;
typedef __attribute__((ext_vector_type(8))) short short8;
typedef unsigned int u32;

#define AS1 __attribute__((address_space(1)))
#define AS3 __attribute__((address_space(3)))

static __device__ __forceinline__ unsigned short f2bf(float f) {
  unsigned int u = __float_as_uint(f);
  u += 0x7fffu + ((u >> 16) & 1u);
  return (unsigned short)(u >> 16);
}

static __device__ __forceinline__ u32 pack2(float x, float y) {
  return (u32)f2bf(x) | ((u32)f2bf(y) << 16);
}

static __device__ __forceinline__ void gload_lds16(const void* g, void* l) {
  __builtin_amdgcn_global_load_lds((const AS1 u32*)g, (AS3 u32*)l, 16, 0, 0);
}

// ---------------- prep: pack_w + cast_mem + hist fused (independent work) -------
// blocks [0,PBLK): pack W'' (512 gates x 384 k) into MFMA B-fragment order.
//   k<128: W_ih src cols. 128<=k<256: W_ih cols 256:384 (tenc+ef). k>=256 (c):
//     g<256 (rz):   W_ih[g,128+c] + W_hh[g,c]   (dst-mean == h folded)
//     256<=g<384:   W_ih[g,128+c]               (i_n dst part; deg==0 fixed up)
//     g>=384 (h_n): W_hh[g-128,c]
// blocks [PBLK,PBLK+CBLK): bf16 pre-cast of si/si_r (gathered arrays).
// blocks [PBLK+CBLK,...): degree histogram (atomics on zeroed deg arrays).
__global__ void prep_kernel(const float* __restrict__ w_ih,
                            const float* __restrict__ w_hh,
                            const float* __restrict__ b_ih,
                            const float* __restrict__ b_hh,
                            unsigned short* __restrict__ Wb,
                            float* __restrict__ bb,
                            const float* __restrict__ si,
                            const float* __restrict__ si_r,
                            unsigned short* __restrict__ si_b,
                            unsigned short* __restrict__ sir_b,
                            const int* __restrict__ dst_g,
                            const int* __restrict__ dst_gr,
                            int* __restrict__ deg_j, int* __restrict__ deg_i,
                            int E) {
  int blk = blockIdx.x;
  if (blk < PBLK) {
    int idx = blk * 256 + threadIdx.x;              // 0 .. 512*384-1
    int j = idx & 7, l = (idx >> 3) & 63, ktt = idx >> 9;   // ktt = tt*12 + kt
    int kt = ktt % 12, tt = ktt / 12;
    int g = tt * 16 + (l & 15);
    int k = kt * 32 + (l >> 4) * 8 + j;
    float v;
    if (k < 128) {
      v = (g < 384) ? w_ih[g * 384 + k] : 0.0f;
    } else if (k < 256) {
      v = (g < 384) ? w_ih[g * 384 + 128 + k] : 0.0f;   // col 256+(k-128)
    } else {
      int c = k - 256;
      if (g < 256)      v = w_ih[g * 384 + 128 + c] + w_hh[g * 128 + c];
      else if (g < 384) v = w_ih[g * 384 + 128 + c];
      else              v = w_hh[(size_t)(g - 128) * 128 + c];
    }
    Wb[idx] = f2bf(v);
    if (idx < 512) {
      float b = (idx < 256) ? (b_ih[idx] + b_hh[idx])
              : (idx < 384) ? b_ih[idx]
                            : b_hh[idx - 128];
      bb[idx] = b;
    }
  } else if (blk < PBLK + CBLK) {
    int i = (blk - PBLK) * 256 + threadIdx.x;       // 0 .. 1,599,999 (8 floats each)
    const float* src; unsigned short* dst; int off;
    if (i < 800000) { src = si;   dst = si_b;  off = i; }
    else            { src = si_r; dst = sir_b; off = i - 800000; }
    const f32x4* p = (const f32x4*)(src + (size_t)off * 8);
    f32x4 a = p[0], b = p[1];
    short8 o;
    o[0] = f2bf(a[0]); o[1] = f2bf(a[1]); o[2] = f2bf(a[2]); o[3] = f2bf(a[3]);
    o[4] = f2bf(b[0]); o[5] = f2bf(b[1]); o[6] = f2bf(b[2]); o[7] = f2bf(b[3]);
    *(short8*)(dst + (size_t)off * 8) = o;
  } else {
    int i = (blk - PBLK - CBLK) * 256 + threadIdx.x;
    if (i < E) atomicAdd(&deg_j[dst_g[i]], 1);
    else if (i < 2 * E) atomicAdd(&deg_i[dst_gr[i - E]], 1);
  }
}

// ---------------- scan: both 50K exclusive prefix sums in ONE block -------------
// 1024 threads; 49 chunk-iterations per direction with an in-register carry.
// Replaces chunksum + chunkscan + localscan (3 launches -> 1, no cross-block dep).
__global__ __launch_bounds__(1024) void scan_kernel(
    const int* __restrict__ deg_j, const int* __restrict__ deg_i,
    int* __restrict__ rs_j, int* __restrict__ cur_j,
    int* __restrict__ rs_i, int* __restrict__ cur_i) {
  __shared__ int wsum[16];
  int t = threadIdx.x, lane = t & 63, w = t >> 6;
  for (int d = 0; d < 2; ++d) {
    const int* deg = d ? deg_i : deg_j;
    int* rs  = d ? rs_i : rs_j;
    int* cur = d ? cur_i : cur_j;
    int carry = 0;
    for (int base = 0; base < NNODE; base += 1024) {
      int idx = base + t;
      int v = (idx < NNODE) ? deg[idx] : 0;
      int x = v;                         // wave inclusive scan
      for (int off = 1; off < 64; off <<= 1) {
        int y = __shfl_up(x, off, 64);
        if (lane >= off) x += y;
      }
      if (lane == 63) wsum[w] = x;
      __syncthreads();
      if (w == 0 && lane < 16) {         // scan the 16 wave sums (lanes 0..15)
        int s = wsum[lane];
        for (int off = 1; off < 16; off <<= 1) {
          int y = __shfl_up(s, off, 64);
          if (lane >= off) s += y;
        }
        wsum[lane] = s;                  // inclusive
      }
      __syncthreads();
      int add = (w > 0) ? wsum[w - 1] : 0;
      int ex = carry + add + x - v;
      if (idx < NNODE) { rs[idx] = ex; cur[idx] = ex; }
      carry += wsum[15];
      __syncthreads();                   // protect wsum reuse next chunk
    }
  }
}

// fill: one 16B record per edge: (src, eid, ts_bits, 0)
__global__ void fill_kernel(const int* __restrict__ src_g, const int* __restrict__ dst_g,
                            const float* __restrict__ t,
                            const int* __restrict__ src_gr, const int* __restrict__ dst_gr,
                            const float* __restrict__ t_r,
                            int* __restrict__ cur_j, int* __restrict__ cur_i,
                            int4* __restrict__ recP_j, int4* __restrict__ recP_i,
                            int E) {
  int i = blockIdx.x * 256 + threadIdx.x;
  if (i < E) {
    int pos = atomicAdd(&cur_j[dst_g[i]], 1);
    recP_j[pos] = make_int4(src_g[i], i, __float_as_int(t[i]), 0);
  } else if (i < 2 * E) {
    int k = i - E;
    int pos = atomicAdd(&cur_i[dst_gr[k]], 1);
    recP_i[pos] = make_int4(src_gr[k], k, __float_as_int(t_r[k]), 0);
  }
}

// ---------------- gather: mean-message, write X row NODE-MAJOR (768B) ----------
// packed k layout: [0,128)=mean src_mem, [128,192)=mean tenc, [192,256)=mean ef,
// [256,384)=h. (h*(deg>0) channel folded into packed weights; deg==0 fixed up.)
__global__ __launch_bounds__(256) void gather_kernel(
    const unsigned short* __restrict__ si_b, const unsigned short* __restrict__ sir_b,
    const float* __restrict__ sj, const float* __restrict__ sj_r,
    const float* __restrict__ e, const float* __restrict__ e_r,
    const int* __restrict__ rs_j, const int* __restrict__ rs_i,
    const int* __restrict__ deg_j, const int* __restrict__ deg_i,
    const int4* __restrict__ recP_j, const int4* __restrict__ recP_i,
    unsigned short* __restrict__ Xb) {
  __shared__ __align__(16) unsigned short rowbuf[4][384];
  int wid = threadIdx.x >> 6, lane = threadIdx.x & 63;
  int gwave = blockIdx.x * 4 + wid;                // 0..NWAVES-1
  // freq[lane] = 10^(-9*lane/63) = exp(-lane * 9/63 * ln 10)
  float freq = __expf((float)lane * -0.3289407276f);
  unsigned short* rb = rowbuf[wid];
  u32* rb32 = (u32*)rb;

  for (int node = gwave; node < NTOT; node += NWAVES) {
    bool user = node < NUSERS;
    int idx = user ? node : node - NUSERS;
    const unsigned short* smem = user ? sir_b : si_b;   // bf16 rows, 128 shorts
    const float* h  = user ? sj_r : sj;
    const float* ef = user ? e_r : e;
    int start = __builtin_amdgcn_readfirstlane((user ? rs_i : rs_j)[idx]);
    int deg   = __builtin_amdgcn_readfirstlane((user ? deg_i : deg_j)[idx]);
    const int4* rec = user ? recP_i : recP_j;

    // h row: issue early, consumed only in the epilogue
    float2 hvf = *(const float2*)(h + (size_t)idx * 128 + 2 * lane);

    float asx = 0.f, asy = 0.f;   // mean src_mem, k = 2*lane, 2*lane+1
    float at  = 0.f;              // tenc, k = 128+lane
    float ae  = 0.f;              // edge feat, k = 192+lane

    for (int base = 0; base < deg; base += 64) {
      int nn = deg - base; if (nn > 64) nn = 64;
      // cooperative record load: lane l holds record base+l (clamped)
      int cl = (lane < nn) ? base + lane : base + nn - 1;
      int4 r = rec[start + cl];
      int full = nn & ~7;
      // ---- unclamped full rounds: no weights, no dup loads ----
      for (int j0 = 0; j0 < full; j0 += 8) {
        int s0 = __builtin_amdgcn_readlane(r.x, j0 + 0), e0 = __builtin_amdgcn_readlane(r.y, j0 + 0);
        int s1 = __builtin_amdgcn_readlane(r.x, j0 + 1), e1 = __builtin_amdgcn_readlane(r.y, j0 + 1);
        int s2 = __builtin_amdgcn_readlane(r.x, j0 + 2), e2 = __builtin_amdgcn_readlane(r.y, j0 + 2);
        int s3 = __builtin_amdgcn_readlane(r.x, j0 + 3), e3 = __builtin_amdgcn_readlane(r.y, j0 + 3);
        int s4 = __builtin_amdgcn_readlane(r.x, j0 + 4), e4 = __builtin_amdgcn_readlane(r.y, j0 + 4);
        int s5 = __builtin_amdgcn_readlane(r.x, j0 + 5), e5 = __builtin_amdgcn_readlane(r.y, j0 + 5);
        int s6 = __builtin_amdgcn_readlane(r.x, j0 + 6), e6 = __builtin_amdgcn_readlane(r.y, j0 + 6);
        int s7 = __builtin_amdgcn_readlane(r.x, j0 + 7), e7 = __builtin_amdgcn_readlane(r.y, j0 + 7);

        u32 v0 = *(const u32*)(smem + ((size_t)s0 << 7) + 2 * lane);
        u32 v1 = *(const u32*)(smem + ((size_t)s1 << 7) + 2 * lane);
        u32 v2 = *(const u32*)(smem + ((size_t)s2 << 7) + 2 * lane);
        u32 v3 = *(const u32*)(smem + ((size_t)s3 << 7) + 2 * lane);
        u32 v4 = *(const u32*)(smem + ((size_t)s4 << 7) + 2 * lane);
        u32 v5 = *(const u32*)(smem + ((size_t)s5 << 7) + 2 * lane);
        u32 v6 = *(const u32*)(smem + ((size_t)s6 << 7) + 2 * lane);
        u32 v7 = *(const u32*)(smem + ((size_t)s7 << 7) + 2 * lane);
        float f0 = ef[((size_t)e0 << 6) + lane];
        float f1 = ef[((size_t)e1 << 6) + lane];
        float f2 = ef[((size_t)e2 << 6) + lane];
        float f3 = ef[((size_t)e3 << 6) + lane];
        float f4 = ef[((size_t)e4 << 6) + lane];
        float f5 = ef[((size_t)e5 << 6) + lane];
        float f6 = ef[((size_t)e6 << 6) + lane];
        float f7 = ef[((size_t)e7 << 6) + lane];

        float c0 = __cosf(__int_as_float(__builtin_amdgcn_readlane(r.z, j0 + 0)) * freq);
        float c1 = __cosf(__int_as_float(__builtin_amdgcn_readlane(r.z, j0 + 1)) * freq);
        float c2 = __cosf(__int_as_float(__builtin_amdgcn_readlane(r.z, j0 + 2)) * freq);
        float c3 = __cosf(__int_as_float(__builtin_amdgcn_readlane(r.z, j0 + 3)) * freq);
        float c4 = __cosf(__int_as_float(__builtin_amdgcn_readlane(r.z, j0 + 4)) * freq);
        float c5 = __cosf(__int_as_float(__builtin_amdgcn_readlane(r.z, j0 + 5)) * freq);
        float c6 = __cosf(__int_as_float(__builtin_amdgcn_readlane(r.z, j0 + 6)) * freq);
        float c7 = __cosf(__int_as_float(__builtin_amdgcn_readlane(r.z, j0 + 7)) * freq);

        float l0 = __uint_as_float(v0 << 16), g0 = __uint_as_float(v0 & 0xffff0000u);
        float l1 = __uint_as_float(v1 << 16), g1 = __uint_as_float(v1 & 0xffff0000u);
        float l2 = __uint_as_float(v2 << 16), g2 = __uint_as_float(v2 & 0xffff0000u);
        float l3 = __uint_as_float(v3 << 16), g3 = __uint_as_float(v3 & 0xffff0000u);
        float l4 = __uint_as_float(v4 << 16), g4 = __uint_as_float(v4 & 0xffff0000u);
        float l5 = __uint_as_float(v5 << 16), g5 = __uint_as_float(v5 & 0xffff0000u);
        float l6 = __uint_as_float(v6 << 16), g6 = __uint_as_float(v6 & 0xffff0000u);
        float l7 = __uint_as_float(v7 << 16), g7 = __uint_as_float(v7 & 0xffff0000u);

        asx += ((l0 + l1) + (l2 + l3)) + ((l4 + l5) + (l6 + l7));
        asy += ((g0 + g1) + (g2 + g3)) + ((g4 + g5) + (g6 + g7));
        at  += ((c0 + c1) + (c2 + c3)) + ((c4 + c5) + (c6 + c7));
        ae  += ((f0 + f1) + (f2 + f3)) + ((f4 + f5) + (f6 + f7));
      }
      // ---- clamped tail (1..7 real edges) ----
      if (full < nn) {
        int j0 = full;
        int j1 = (j0 + 1 < nn) ? j0 + 1 : nn - 1;
        int j2 = (j0 + 2 < nn) ? j0 + 2 : nn - 1;
        int j3 = (j0 + 3 < nn) ? j0 + 3 : nn - 1;
        int j4 = (j0 + 4 < nn) ? j0 + 4 : nn - 1;
        int j5 = (j0 + 5 < nn) ? j0 + 5 : nn - 1;
        int j6 = (j0 + 6 < nn) ? j0 + 6 : nn - 1;
        float w1 = (j0 + 1 < nn) ? 1.0f : 0.0f;
        float w2 = (j0 + 2 < nn) ? 1.0f : 0.0f;
        float w3 = (j0 + 3 < nn) ? 1.0f : 0.0f;
        float w4 = (j0 + 4 < nn) ? 1.0f : 0.0f;
        float w5 = (j0 + 5 < nn) ? 1.0f : 0.0f;
        float w6 = (j0 + 6 < nn) ? 1.0f : 0.0f;

        int s0 = __builtin_amdgcn_readlane(r.x, j0), e0 = __builtin_amdgcn_readlane(r.y, j0);
        int s1 = __builtin_amdgcn_readlane(r.x, j1), e1 = __builtin_amdgcn_readlane(r.y, j1);
        int s2 = __builtin_amdgcn_readlane(r.x, j2), e2 = __builtin_amdgcn_readlane(r.y, j2);
        int s3 = __builtin_amdgcn_readlane(r.x, j3), e3 = __builtin_amdgcn_readlane(r.y, j3);
        int s4 = __builtin_amdgcn_readlane(r.x, j4), e4 = __builtin_amdgcn_readlane(r.y, j4);
        int s5 = __builtin_amdgcn_readlane(r.x, j5), e5 = __builtin_amdgcn_readlane(r.y, j5);
        int s6 = __builtin_amdgcn_readlane(r.x, j6), e6 = __builtin_amdgcn_readlane(r.y, j6);

        u32 v0 = *(const u32*)(smem + ((size_t)s0 << 7) + 2 * lane);
        u32 v1 = *(const u32*)(smem + ((size_t)s1 << 7) + 2 * lane);
        u32 v2 = *(const u32*)(smem + ((size_t)s2 << 7) + 2 * lane);
        u32 v3 = *(const u32*)(smem + ((size_t)s3 << 7) + 2 * lane);
        u32 v4 = *(const u32*)(smem + ((size_t)s4 << 7) + 2 * lane);
        u32 v5 = *(const u32*)(smem + ((size_t)s5 << 7) + 2 * lane);
        u32 v6 = *(const u32*)(smem + ((size_t)s6 << 7) + 2 * lane);
        float f0 = ef[((size_t)e0 << 6) + lane];
        float f1 = ef[((size_t)e1 << 6) + lane];
        float f2 = ef[((size_t)e2 << 6) + lane];
        float f3 = ef[((size_t)e3 << 6) + lane];
        float f4 = ef[((size_t)e4 << 6) + lane];
        float f5 = ef[((size_t)e5 << 6) + lane];
        float f6 = ef[((size_t)e6 << 6) + lane];

        float c0 = __cosf(__int_as_float(__builtin_amdgcn_readlane(r.z, j0)) * freq);
        float c1 = __cosf(__int_as_float(__builtin_amdgcn_readlane(r.z, j1)) * freq);
        float c2 = __cosf(__int_as_float(__builtin_amdgcn_readlane(r.z, j2)) * freq);
        float c3 = __cosf(__int_as_float(__builtin_amdgcn_readlane(r.z, j3)) * freq);
        float c4 = __cosf(__int_as_float(__builtin_amdgcn_readlane(r.z, j4)) * freq);
        float c5 = __cosf(__int_as_float(__builtin_amdgcn_readlane(r.z, j5)) * freq);
        float c6 = __cosf(__int_as_float(__builtin_amdgcn_readlane(r.z, j6)) * freq);

        float l0 = __uint_as_float(v0 << 16), g0 = __uint_as_float(v0 & 0xffff0000u);
        float l1 = __uint_as_float(v1 << 16), g1 = __uint_as_float(v1 & 0xffff0000u);
        float l2 = __uint_as_float(v2 << 16), g2 = __uint_as_float(v2 & 0xffff0000u);
        float l3 = __uint_as_float(v3 << 16), g3 = __uint_as_float(v3 & 0xffff0000u);
        float l4 = __uint_as_float(v4 << 16), g4 = __uint_as_float(v4 & 0xffff0000u);
        float l5 = __uint_as_float(v5 << 16), g5 = __uint_as_float(v5 & 0xffff0000u);
        float l6 = __uint_as_float(v6 << 16), g6 = __uint_as_float(v6 & 0xffff0000u);

        asx += l0 + w1 * l1 + w2 * l2 + w3 * l3 + w4 * l4 + w5 * l5 + w6 * l6;
        asy += g0 + w1 * g1 + w2 * g2 + w3 * g3 + w4 * g4 + w5 * g5 + w6 * g6;
        at  += c0 + w1 * c1 + w2 * c2 + w3 * c3 + w4 * c4 + w5 * c5 + w6 * c6;
        ae  += f0 + w1 * f1 + w2 * f2 + w3 * f3 + w4 * f4 + w5 * f5 + w6 * f6;
      }
    }

    float invc = (deg > 0) ? 1.0f / (float)deg : 0.0f;

    rb32[lane]       = pack2(asx * invc, asy * invc);   // k = 2*lane,2*lane+1
    rb[128 + lane]   = f2bf(at * invc);                 // k = 128+lane
    rb[192 + lane]   = f2bf(ae * invc);                 // k = 192+lane
    rb32[128 + lane] = pack2(hvf.x, hvf.y);             // k = 256+2*lane

    // wave-private LDS transpose, then node-major row write (768B contiguous)
    if (lane < 48) {
      short8 vv = *(const short8*)(rb + lane * 8);
      *(short8*)(Xb + (size_t)node * KDIM + lane * 8) = vv;
    }
  }
}

// ---------------- GEMM (100000 x 384) @ W''^T with fused GRU epilogue ----------------
// v12 structure (two barrier domains/CU) at K=384 (12 kt steps). Block = 512 thr /
// 8 waves, tile 4 mtiles x 512 out-cols. LDS = sA 2x4KB + sW 2x32KB = 72KB -> 2
// blocks/CU. Wave = 2 mtiles x 128 cols, ~125 VGPR.
__global__ __launch_bounds__(512, 4) void gemm_gru_kernel(
    const unsigned short* __restrict__ Xb,
    const unsigned short* __restrict__ Wb,
    const float* __restrict__ bb,
    const float* __restrict__ sj_r,
    const float* __restrict__ sj,
    float* __restrict__ out) {
  __shared__ __align__(16) unsigned short sA[2][2048];    // 2 x 4 KB : [mt4][512]
  __shared__ __align__(16) unsigned short sW[2][16384];   // 2 x 32 KB: [tt32][512]
  int wid = threadIdx.x >> 6, lane = threadIdx.x & 63;
  int mg = wid >> 2, cg = wid & 3;         // m-group 0..1, col-group 0..3
  int mbase = blockIdx.x * 4;
  int col16 = lane & 15, quad = lane >> 4;

  // staging sources: wave wid stages W slices tt = wid*4..wid*4+3;
  // waves 0..3 additionally stage A slice mt4 = wid.
  int mts = mbase + (wid & 3); if (mts >= MTILES) mts = MTILES - 1;
  const unsigned short* gA = Xb + (size_t)(mts * 16 + col16) * KDIM + quad * 8;
  const unsigned short* gB = Wb + (size_t)(wid * 4) * 12 * 512 + lane * 8;

#define STG(buf, kt)                                                          \
  {                                                                           \
    _Pragma("unroll")                                                         \
    for (int i = 0; i < 4; ++i)                                               \
      gload_lds16(gB + ((size_t)(i * 12 + (kt))) * 512, sW[buf] + (wid * 4 + i) * 512); \
    if (wid < 4) gload_lds16(gA + (kt) * 32, sA[buf] + (wid & 3) * 512);      \
  }

  f32x4 acc[2][8];                         // [mi][g*2+nt]
#pragma unroll
  for (int mi = 0; mi < 2; ++mi)
#pragma unroll
    for (int t8 = 0; t8 < 8; ++t8) acc[mi][t8] = (f32x4)0.0f;

  STG(0, 0)
  __syncthreads();

  for (int kt = 0; kt < 12; ++kt) {
    int cur = kt & 1;
    if (kt < 11) STG(cur ^ 1, kt + 1)
    short8 a[2], b[8];
#pragma unroll
    for (int mi = 0; mi < 2; ++mi)
      a[mi] = *(const short8*)(sA[cur] + (mg * 2 + mi) * 512 + lane * 8);
#pragma unroll
    for (int g = 0; g < 4; ++g)
#pragma unroll
      for (int nt = 0; nt < 2; ++nt)
        b[g * 2 + nt] = *(const short8*)(sW[cur] + (g * 8 + cg * 2 + nt) * 512 + lane * 8);
#pragma unroll
    for (int mi = 0; mi < 2; ++mi)
#pragma unroll
      for (int t8 = 0; t8 < 8; ++t8)
        acc[mi][t8] = __builtin_amdgcn_mfma_f32_16x16x32_bf16(a[mi], b[t8], acc[mi][t8], 0, 0, 0);
    __syncthreads();
  }

  // fused GRU epilogue: wave owns out cols (cg*2+nt)*16+col16, rows = its 2 mtiles
#pragma unroll
  for (int nt = 0; nt < 2; ++nt) {
    int cc = (cg * 2 + nt) * 16 + col16;
    float bbr = bb[cc], bbz = bb[128 + cc], bbn = bb[256 + cc], bbh = bb[384 + cc];
#pragma unroll
    for (int mi = 0; mi < 2; ++mi) {
      int mt = mbase + mg * 2 + mi;
      if (mt >= MTILES) continue;
#pragma unroll
      for (int r = 0; r < 4; ++r) {
        int row = mt * 16 + quad * 4 + r;
        float rp  = acc[mi][0 + nt][r] + bbr;   // gate r: t8 = 0*2+nt
        float zp  = acc[mi][2 + nt][r] + bbz;   // gate z: t8 = 1*2+nt
        float inp = acc[mi][4 + nt][r] + bbn;   // gate n: t8 = 2*2+nt
        float hnp = acc[mi][6 + nt][r] + bbh;   // gate h: t8 = 3*2+nt
        float rg = 1.0f / (1.0f + __expf(-rp));
        float zg = 1.0f / (1.0f + __expf(-zp));
        float ng = tanhf(inp + rg * hnp);
        float hv = (row < NUSERS) ? sj_r[(size_t)row * 128 + cc]
                                  : sj[(size_t)(row - NUSERS) * 128 + cc];
        out[(size_t)row * 128 + cc] = (1.0f - zg) * ng + zg * hv;
      }
    }
  }
}

// ---------------- fixup: deg==0 nodes (weight fold invalid there) --------------
// For deg==0: x = 0 -> gi = b_ih; gh = h@W_hh^T + b_hh. ~34 nodes expected.
__global__ __launch_bounds__(256) void fixup_kernel(
    const int* __restrict__ deg_j, const int* __restrict__ deg_i,
    const float* __restrict__ sj, const float* __restrict__ sj_r,
    const float* __restrict__ w_hh, const float* __restrict__ b_ih,
    const float* __restrict__ b_hh, float* __restrict__ out) {
  int w = blockIdx.x * 4 + (threadIdx.x >> 6), lane = threadIdx.x & 63;
  long base = (long)w * 64;
  if (base >= NTOT) return;
  int node = (int)base + lane;
  int dg = 1;
  if (node < NTOT) {
    bool user = node < NUSERS;
    dg = user ? deg_i[node] : deg_j[node - NUSERS];
  }
  unsigned long long zm = __ballot(dg == 0);
  while (zm) {
    int b = __ffsll((long long)zm) - 1; zm &= zm - 1;
    int zn = (int)base + b;
    bool zu = zn < NUSERS;
    const float* h = zu ? (sj_r + (size_t)zn * 128) : (sj + (size_t)(zn - NUSERS) * 128);
#pragma unroll
    for (int half = 0; half < 2; ++half) {
      int c = half * 64 + lane;
      float gr = 0.f, gz = 0.f, gn = 0.f;
      for (int k = 0; k < 128; ++k) {
        float hk = h[k];
        gr += w_hh[(size_t)c * 128 + k] * hk;
        gz += w_hh[(size_t)(128 + c) * 128 + k] * hk;
        gn += w_hh[(size_t)(256 + c) * 128 + k] * hk;
      }
      float rg = 1.0f / (1.0f + __expf(-(b_ih[c] + b_hh[c] + gr)));
      float zg = 1.0f / (1.0f + __expf(-(b_ih[128 + c] + b_hh[128 + c] + gz)));
      float ng = tanhf(b_ih[256 + c] + rg * (b_hh[256 + c] + gn));
      out[(size_t)zn * 128 + c] = (1.0f - zg) * ng + zg * h[c];
    }
  }
}

extern "C" void kernel_launch(void* const* d_in, const int* in_sizes, int n_in,
                              void* d_out, int out_size, void* d_ws, size_t ws_size,
                              hipStream_t stream) {
  const float* si   = (const float*)d_in[0];
  const float* sj   = (const float*)d_in[1];
  const float* si_r = (const float*)d_in[2];
  const float* sj_r = (const float*)d_in[3];
  const float* t    = (const float*)d_in[4];
  const float* t_r  = (const float*)d_in[5];
  const float* e    = (const float*)d_in[6];
  const float* e_r  = (const float*)d_in[7];
  const float* w_ih = (const float*)d_in[8];
  const float* w_hh = (const float*)d_in[9];
  const float* b_ih = (const float*)d_in[10];
  const float* b_hh = (const float*)d_in[11];
  const int* src_g  = (const int*)d_in[12];
  const int* dst_g  = (const int*)d_in[13];
  const int* src_gr = (const int*)d_in[14];
  const int* dst_gr = (const int*)d_in[15];
  int E = in_sizes[4];

  // workspace layout (16B-aligned head first)
  unsigned short* Xb = (unsigned short*)d_ws;          // NTOT*384 shorts (76.8 MB), node-major
  unsigned short* Wb = Xb + (size_t)NTOT * KDIM;       // 512*384 = 196608 shorts
  float* bb   = (float*)(Wb + 196608);                 // 512
  int* deg_j  = (int*)(bb + 512);                      // 50000  (memset target, with deg_i)
  int* deg_i  = deg_j + NNODE;                         // 50000
  int* rs_j   = deg_i + NNODE;                         // 50000
  int* rs_i   = rs_j + NNODE;                          // 50000
  int* cur_j  = rs_i + NNODE;                          // 50000
  int* cur_i  = cur_j + NNODE;                         // 50000 (ends 16B-aligned)
  int4* recP_j = (int4*)(cur_i + NNODE);               // E int4
  int4* recP_i = recP_j + E;                           // E int4
  unsigned short* si_b  = (unsigned short*)(recP_i + E);  // 6.4M shorts (12.8 MB)
  unsigned short* sir_b = si_b + 6400000;                 // 6.4M shorts (12.8 MB)

  hipMemsetAsync(deg_j, 0, 2 * NNODE * sizeof(int), stream);

  int hblks = (2 * E + 255) / 256;
  prep_kernel<<<PBLK + CBLK + hblks, 256, 0, stream>>>(
      w_ih, w_hh, b_ih, b_hh, Wb, bb,
      si, si_r, si_b, sir_b,
      dst_g, dst_gr, deg_j, deg_i, E);

  scan_kernel<<<1, 1024, 0, stream>>>(deg_j, deg_i, rs_j, cur_j, rs_i, cur_i);

  fill_kernel<<<hblks, 256, 0, stream>>>(src_g, dst_g, t, src_gr, dst_gr, t_r,
                                         cur_j, cur_i, recP_j, recP_i, E);

  gather_kernel<<<NWAVES / 4, 256, 0, stream>>>(si_b, sir_b, sj, sj_r, e, e_r,
                                                rs_j, rs_i, deg_j, deg_i,
                                                recP_j, recP_i, Xb);

  float* out = (float*)d_out;
  gemm_gru_kernel<<<(MTILES + 3) / 4, 512, 0, stream>>>(Xb, Wb, bb, sj_r, sj, out);
  fixup_kernel<<<391, 256, 0, stream>>>(deg_j, deg_i, sj, sj_r, w_hh, b_ih, b_hh, out);
}

// Round 14
// 567.707 us; speedup vs baseline: 1.1250x; 1.1250x over previous
//
#include <hip/hip_runtime.h>
#include <math.h>

#define NUSERS 50000
#define NITEMS 50000
#define NTOT   100000
#define NNODE  50000      // per direction
#define NCHUNK 196        // ceil(50000/256)
#define MTILES 6250       // 100000/16 row tiles
#define KDIM   384        // folded K: [mean_src 128 | tenc 64 | ef 64 | h 128]
#define NWAVES 8192       // gather: 2048 blocks x 4 waves, grid-stride over nodes
#define PBLK   768        // prep: pack_w blocks (512*384/256)
#define CBLK   6250       // prep: cast_mem blocks

typedef __attribute__((ext_vector_type(4))) float f32x4;
typedef __attribute__((ext_vector_type(8))) short short8;
typedef unsigned int u32;

#define AS1 __attribute__((address_space(1)))
#define AS3 __attribute__((address_space(3)))

static __device__ __forceinline__ unsigned short f2bf(float f) {
  unsigned int u = __float_as_uint(f);
  u += 0x7fffu + ((u >> 16) & 1u);
  return (unsigned short)(u >> 16);
}

static __device__ __forceinline__ u32 pack2(float x, float y) {
  return (u32)f2bf(x) | ((u32)f2bf(y) << 16);
}

static __device__ __forceinline__ void gload_lds16(const void* g, void* l) {
  __builtin_amdgcn_global_load_lds((const AS1 u32*)g, (AS3 u32*)l, 16, 0, 0);
}

// ---------------- prep: pack_w + cast_mem + hist fused (independent work) -------
// blocks [0,PBLK): pack W'' (512 gates x 384 k) into MFMA B-fragment order.
//   k<128: W_ih src cols. 128<=k<256: W_ih cols 256:384 (tenc+ef). k>=256 (c):
//     g<256 (rz):   W_ih[g,128+c] + W_hh[g,c]   (dst-mean == h folded)
//     256<=g<384:   W_ih[g,128+c]               (i_n dst part; deg==0 fixed up)
//     g>=384 (h_n): W_hh[g-128,c]
// blocks [PBLK,PBLK+CBLK): bf16 pre-cast of si/si_r (gathered arrays).
// blocks [PBLK+CBLK,...): degree histogram (atomics on zeroed deg arrays).
__global__ void prep_kernel(const float* __restrict__ w_ih,
                            const float* __restrict__ w_hh,
                            const float* __restrict__ b_ih,
                            const float* __restrict__ b_hh,
                            unsigned short* __restrict__ Wb,
                            float* __restrict__ bb,
                            const float* __restrict__ si,
                            const float* __restrict__ si_r,
                            unsigned short* __restrict__ si_b,
                            unsigned short* __restrict__ sir_b,
                            const int* __restrict__ dst_g,
                            const int* __restrict__ dst_gr,
                            int* __restrict__ deg_j, int* __restrict__ deg_i,
                            int E) {
  int blk = blockIdx.x;
  if (blk < PBLK) {
    int idx = blk * 256 + threadIdx.x;              // 0 .. 512*384-1
    int j = idx & 7, l = (idx >> 3) & 63, ktt = idx >> 9;   // ktt = tt*12 + kt
    int kt = ktt % 12, tt = ktt / 12;
    int g = tt * 16 + (l & 15);
    int k = kt * 32 + (l >> 4) * 8 + j;
    float v;
    if (k < 128) {
      v = (g < 384) ? w_ih[g * 384 + k] : 0.0f;
    } else if (k < 256) {
      v = (g < 384) ? w_ih[g * 384 + 128 + k] : 0.0f;   // col 256+(k-128)
    } else {
      int c = k - 256;
      if (g < 256)      v = w_ih[g * 384 + 128 + c] + w_hh[g * 128 + c];
      else if (g < 384) v = w_ih[g * 384 + 128 + c];
      else              v = w_hh[(size_t)(g - 128) * 128 + c];
    }
    Wb[idx] = f2bf(v);
    if (idx < 512) {
      float b = (idx < 256) ? (b_ih[idx] + b_hh[idx])
              : (idx < 384) ? b_ih[idx]
                            : b_hh[idx - 128];
      bb[idx] = b;
    }
  } else if (blk < PBLK + CBLK) {
    int i = (blk - PBLK) * 256 + threadIdx.x;       // 0 .. 1,599,999 (8 floats each)
    const float* src; unsigned short* dst; int off;
    if (i < 800000) { src = si;   dst = si_b;  off = i; }
    else            { src = si_r; dst = sir_b; off = i - 800000; }
    const f32x4* p = (const f32x4*)(src + (size_t)off * 8);
    f32x4 a = p[0], b = p[1];
    short8 o;
    o[0] = f2bf(a[0]); o[1] = f2bf(a[1]); o[2] = f2bf(a[2]); o[3] = f2bf(a[3]);
    o[4] = f2bf(b[0]); o[5] = f2bf(b[1]); o[6] = f2bf(b[2]); o[7] = f2bf(b[3]);
    *(short8*)(dst + (size_t)off * 8) = o;
  } else {
    int i = (blk - PBLK - CBLK) * 256 + threadIdx.x;
    if (i < E) atomicAdd(&deg_j[dst_g[i]], 1);
    else if (i < 2 * E) atomicAdd(&deg_i[dst_gr[i - E]], 1);
  }
}

// ---------------- CSR scan: proven 3-kernel chain (round-12) -----------------
__global__ void chunksum_kernel(const int* __restrict__ deg_j,
                                const int* __restrict__ deg_i,
                                int* __restrict__ csum) {
  int c = blockIdx.x;                    // 0..2*NCHUNK-1
  const int* deg = (c < NCHUNK) ? deg_j : deg_i;
  int cc = (c < NCHUNK) ? c : c - NCHUNK;
  int t = threadIdx.x;
  int idx = cc * 256 + t;
  int v = (idx < NNODE) ? deg[idx] : 0;
  for (int off = 32; off; off >>= 1) v += __shfl_down(v, off, 64);
  __shared__ int wsum[4];
  if ((t & 63) == 0) wsum[t >> 6] = v;
  __syncthreads();
  if (t == 0) csum[c] = wsum[0] + wsum[1] + wsum[2] + wsum[3];
}

__global__ void chunkscan_kernel(const int* __restrict__ csum, int* __restrict__ coff) {
  int d = blockIdx.x;                    // 0 or 1
  const int* cs = csum + d * NCHUNK;
  int* co = coff + d * NCHUNK;
  int t = threadIdx.x, lane = t & 63, w = t >> 6;
  int v = (t < NCHUNK) ? cs[t] : 0;
  int x = v;
  for (int off = 1; off < 64; off <<= 1) {
    int y = __shfl_up(x, off, 64);
    if (lane >= off) x += y;
  }
  __shared__ int wt[4];
  if (lane == 63) wt[w] = x;
  __syncthreads();
  int add = 0;
  for (int k = 0; k < 4; ++k) if (k < w) add += wt[k];
  if (t < NCHUNK) co[t] = add + x - v;   // exclusive prefix
}

__global__ void localscan_kernel(const int* __restrict__ deg_j,
                                 const int* __restrict__ deg_i,
                                 const int* __restrict__ coff,
                                 int* __restrict__ rs_j, int* __restrict__ cur_j,
                                 int* __restrict__ rs_i, int* __restrict__ cur_i) {
  int c = blockIdx.x;
  bool dj = c < NCHUNK;
  const int* deg = dj ? deg_j : deg_i;
  int cc = dj ? c : c - NCHUNK;
  int* rs = dj ? rs_j : rs_i;
  int* cur = dj ? cur_j : cur_i;
  int base = coff[c];
  int t = threadIdx.x, lane = t & 63, w = t >> 6;
  int idx = cc * 256 + t;
  int v = (idx < NNODE) ? deg[idx] : 0;
  int x = v;
  for (int off = 1; off < 64; off <<= 1) {
    int y = __shfl_up(x, off, 64);
    if (lane >= off) x += y;
  }
  __shared__ int wt[4];
  if (lane == 63) wt[w] = x;
  __syncthreads();
  int add = 0;
  for (int k = 0; k < 4; ++k) if (k < w) add += wt[k];
  int ex = base + add + x - v;
  if (idx < NNODE) { rs[idx] = ex; cur[idx] = ex; }
}

// fill: one 16B record per edge: (src, eid, ts_bits, 0)
__global__ void fill_kernel(const int* __restrict__ src_g, const int* __restrict__ dst_g,
                            const float* __restrict__ t,
                            const int* __restrict__ src_gr, const int* __restrict__ dst_gr,
                            const float* __restrict__ t_r,
                            int* __restrict__ cur_j, int* __restrict__ cur_i,
                            int4* __restrict__ recP_j, int4* __restrict__ recP_i,
                            int E) {
  int i = blockIdx.x * 256 + threadIdx.x;
  if (i < E) {
    int pos = atomicAdd(&cur_j[dst_g[i]], 1);
    recP_j[pos] = make_int4(src_g[i], i, __float_as_int(t[i]), 0);
  } else if (i < 2 * E) {
    int k = i - E;
    int pos = atomicAdd(&cur_i[dst_gr[k]], 1);
    recP_i[pos] = make_int4(src_gr[k], k, __float_as_int(t_r[k]), 0);
  }
}

// ---------------- gather: mean-message, write X row NODE-MAJOR (768B) ----------
// packed k layout: [0,128)=mean src_mem, [128,192)=mean tenc, [192,256)=mean ef,
// [256,384)=h. (h*(deg>0) channel folded into packed weights; deg==0 fixed up.)
__global__ __launch_bounds__(256) void gather_kernel(
    const unsigned short* __restrict__ si_b, const unsigned short* __restrict__ sir_b,
    const float* __restrict__ sj, const float* __restrict__ sj_r,
    const float* __restrict__ e, const float* __restrict__ e_r,
    const int* __restrict__ rs_j, const int* __restrict__ rs_i,
    const int* __restrict__ deg_j, const int* __restrict__ deg_i,
    const int4* __restrict__ recP_j, const int4* __restrict__ recP_i,
    unsigned short* __restrict__ Xb) {
  __shared__ __align__(16) unsigned short rowbuf[4][384];
  int wid = threadIdx.x >> 6, lane = threadIdx.x & 63;
  int gwave = blockIdx.x * 4 + wid;                // 0..NWAVES-1
  // freq[lane] = 10^(-9*lane/63) = exp(-lane * 9/63 * ln 10)
  float freq = __expf((float)lane * -0.3289407276f);
  unsigned short* rb = rowbuf[wid];
  u32* rb32 = (u32*)rb;

  for (int node = gwave; node < NTOT; node += NWAVES) {
    bool user = node < NUSERS;
    int idx = user ? node : node - NUSERS;
    const unsigned short* smem = user ? sir_b : si_b;   // bf16 rows, 128 shorts
    const float* h  = user ? sj_r : sj;
    const float* ef = user ? e_r : e;
    int start = __builtin_amdgcn_readfirstlane((user ? rs_i : rs_j)[idx]);
    int deg   = __builtin_amdgcn_readfirstlane((user ? deg_i : deg_j)[idx]);
    const int4* rec = user ? recP_i : recP_j;

    // h row: issue early, consumed only in the epilogue
    float2 hvf = *(const float2*)(h + (size_t)idx * 128 + 2 * lane);

    float asx = 0.f, asy = 0.f;   // mean src_mem, k = 2*lane, 2*lane+1
    float at  = 0.f;              // tenc, k = 128+lane
    float ae  = 0.f;              // edge feat, k = 192+lane

    for (int base = 0; base < deg; base += 64) {
      int nn = deg - base; if (nn > 64) nn = 64;
      // cooperative record load: lane l holds record base+l (clamped)
      int cl = (lane < nn) ? base + lane : base + nn - 1;
      int4 r = rec[start + cl];
      int full = nn & ~7;
      // ---- unclamped full rounds: no weights, no dup loads ----
      for (int j0 = 0; j0 < full; j0 += 8) {
        int s0 = __builtin_amdgcn_readlane(r.x, j0 + 0), e0 = __builtin_amdgcn_readlane(r.y, j0 + 0);
        int s1 = __builtin_amdgcn_readlane(r.x, j0 + 1), e1 = __builtin_amdgcn_readlane(r.y, j0 + 1);
        int s2 = __builtin_amdgcn_readlane(r.x, j0 + 2), e2 = __builtin_amdgcn_readlane(r.y, j0 + 2);
        int s3 = __builtin_amdgcn_readlane(r.x, j0 + 3), e3 = __builtin_amdgcn_readlane(r.y, j0 + 3);
        int s4 = __builtin_amdgcn_readlane(r.x, j0 + 4), e4 = __builtin_amdgcn_readlane(r.y, j0 + 4);
        int s5 = __builtin_amdgcn_readlane(r.x, j0 + 5), e5 = __builtin_amdgcn_readlane(r.y, j0 + 5);
        int s6 = __builtin_amdgcn_readlane(r.x, j0 + 6), e6 = __builtin_amdgcn_readlane(r.y, j0 + 6);
        int s7 = __builtin_amdgcn_readlane(r.x, j0 + 7), e7 = __builtin_amdgcn_readlane(r.y, j0 + 7);

        u32 v0 = *(const u32*)(smem + ((size_t)s0 << 7) + 2 * lane);
        u32 v1 = *(const u32*)(smem + ((size_t)s1 << 7) + 2 * lane);
        u32 v2 = *(const u32*)(smem + ((size_t)s2 << 7) + 2 * lane);
        u32 v3 = *(const u32*)(smem + ((size_t)s3 << 7) + 2 * lane);
        u32 v4 = *(const u32*)(smem + ((size_t)s4 << 7) + 2 * lane);
        u32 v5 = *(const u32*)(smem + ((size_t)s5 << 7) + 2 * lane);
        u32 v6 = *(const u32*)(smem + ((size_t)s6 << 7) + 2 * lane);
        u32 v7 = *(const u32*)(smem + ((size_t)s7 << 7) + 2 * lane);
        float f0 = ef[((size_t)e0 << 6) + lane];
        float f1 = ef[((size_t)e1 << 6) + lane];
        float f2 = ef[((size_t)e2 << 6) + lane];
        float f3 = ef[((size_t)e3 << 6) + lane];
        float f4 = ef[((size_t)e4 << 6) + lane];
        float f5 = ef[((size_t)e5 << 6) + lane];
        float f6 = ef[((size_t)e6 << 6) + lane];
        float f7 = ef[((size_t)e7 << 6) + lane];

        float c0 = __cosf(__int_as_float(__builtin_amdgcn_readlane(r.z, j0 + 0)) * freq);
        float c1 = __cosf(__int_as_float(__builtin_amdgcn_readlane(r.z, j0 + 1)) * freq);
        float c2 = __cosf(__int_as_float(__builtin_amdgcn_readlane(r.z, j0 + 2)) * freq);
        float c3 = __cosf(__int_as_float(__builtin_amdgcn_readlane(r.z, j0 + 3)) * freq);
        float c4 = __cosf(__int_as_float(__builtin_amdgcn_readlane(r.z, j0 + 4)) * freq);
        float c5 = __cosf(__int_as_float(__builtin_amdgcn_readlane(r.z, j0 + 5)) * freq);
        float c6 = __cosf(__int_as_float(__builtin_amdgcn_readlane(r.z, j0 + 6)) * freq);
        float c7 = __cosf(__int_as_float(__builtin_amdgcn_readlane(r.z, j0 + 7)) * freq);

        float l0 = __uint_as_float(v0 << 16), g0 = __uint_as_float(v0 & 0xffff0000u);
        float l1 = __uint_as_float(v1 << 16), g1 = __uint_as_float(v1 & 0xffff0000u);
        float l2 = __uint_as_float(v2 << 16), g2 = __uint_as_float(v2 & 0xffff0000u);
        float l3 = __uint_as_float(v3 << 16), g3 = __uint_as_float(v3 & 0xffff0000u);
        float l4 = __uint_as_float(v4 << 16), g4 = __uint_as_float(v4 & 0xffff0000u);
        float l5 = __uint_as_float(v5 << 16), g5 = __uint_as_float(v5 & 0xffff0000u);
        float l6 = __uint_as_float(v6 << 16), g6 = __uint_as_float(v6 & 0xffff0000u);
        float l7 = __uint_as_float(v7 << 16), g7 = __uint_as_float(v7 & 0xffff0000u);

        asx += ((l0 + l1) + (l2 + l3)) + ((l4 + l5) + (l6 + l7));
        asy += ((g0 + g1) + (g2 + g3)) + ((g4 + g5) + (g6 + g7));
        at  += ((c0 + c1) + (c2 + c3)) + ((c4 + c5) + (c6 + c7));
        ae  += ((f0 + f1) + (f2 + f3)) + ((f4 + f5) + (f6 + f7));
      }
      // ---- clamped tail (1..7 real edges) ----
      if (full < nn) {
        int j0 = full;
        int j1 = (j0 + 1 < nn) ? j0 + 1 : nn - 1;
        int j2 = (j0 + 2 < nn) ? j0 + 2 : nn - 1;
        int j3 = (j0 + 3 < nn) ? j0 + 3 : nn - 1;
        int j4 = (j0 + 4 < nn) ? j0 + 4 : nn - 1;
        int j5 = (j0 + 5 < nn) ? j0 + 5 : nn - 1;
        int j6 = (j0 + 6 < nn) ? j0 + 6 : nn - 1;
        float w1 = (j0 + 1 < nn) ? 1.0f : 0.0f;
        float w2 = (j0 + 2 < nn) ? 1.0f : 0.0f;
        float w3 = (j0 + 3 < nn) ? 1.0f : 0.0f;
        float w4 = (j0 + 4 < nn) ? 1.0f : 0.0f;
        float w5 = (j0 + 5 < nn) ? 1.0f : 0.0f;
        float w6 = (j0 + 6 < nn) ? 1.0f : 0.0f;

        int s0 = __builtin_amdgcn_readlane(r.x, j0), e0 = __builtin_amdgcn_readlane(r.y, j0);
        int s1 = __builtin_amdgcn_readlane(r.x, j1), e1 = __builtin_amdgcn_readlane(r.y, j1);
        int s2 = __builtin_amdgcn_readlane(r.x, j2), e2 = __builtin_amdgcn_readlane(r.y, j2);
        int s3 = __builtin_amdgcn_readlane(r.x, j3), e3 = __builtin_amdgcn_readlane(r.y, j3);
        int s4 = __builtin_amdgcn_readlane(r.x, j4), e4 = __builtin_amdgcn_readlane(r.y, j4);
        int s5 = __builtin_amdgcn_readlane(r.x, j5), e5 = __builtin_amdgcn_readlane(r.y, j5);
        int s6 = __builtin_amdgcn_readlane(r.x, j6), e6 = __builtin_amdgcn_readlane(r.y, j6);

        u32 v0 = *(const u32*)(smem + ((size_t)s0 << 7) + 2 * lane);
        u32 v1 = *(const u32*)(smem + ((size_t)s1 << 7) + 2 * lane);
        u32 v2 = *(const u32*)(smem + ((size_t)s2 << 7) + 2 * lane);
        u32 v3 = *(const u32*)(smem + ((size_t)s3 << 7) + 2 * lane);
        u32 v4 = *(const u32*)(smem + ((size_t)s4 << 7) + 2 * lane);
        u32 v5 = *(const u32*)(smem + ((size_t)s5 << 7) + 2 * lane);
        u32 v6 = *(const u32*)(smem + ((size_t)s6 << 7) + 2 * lane);
        float f0 = ef[((size_t)e0 << 6) + lane];
        float f1 = ef[((size_t)e1 << 6) + lane];
        float f2 = ef[((size_t)e2 << 6) + lane];
        float f3 = ef[((size_t)e3 << 6) + lane];
        float f4 = ef[((size_t)e4 << 6) + lane];
        float f5 = ef[((size_t)e5 << 6) + lane];
        float f6 = ef[((size_t)e6 << 6) + lane];

        float c0 = __cosf(__int_as_float(__builtin_amdgcn_readlane(r.z, j0)) * freq);
        float c1 = __cosf(__int_as_float(__builtin_amdgcn_readlane(r.z, j1)) * freq);
        float c2 = __cosf(__int_as_float(__builtin_amdgcn_readlane(r.z, j2)) * freq);
        float c3 = __cosf(__int_as_float(__builtin_amdgcn_readlane(r.z, j3)) * freq);
        float c4 = __cosf(__int_as_float(__builtin_amdgcn_readlane(r.z, j4)) * freq);
        float c5 = __cosf(__int_as_float(__builtin_amdgcn_readlane(r.z, j5)) * freq);
        float c6 = __cosf(__int_as_float(__builtin_amdgcn_readlane(r.z, j6)) * freq);

        float l0 = __uint_as_float(v0 << 16), g0 = __uint_as_float(v0 & 0xffff0000u);
        float l1 = __uint_as_float(v1 << 16), g1 = __uint_as_float(v1 & 0xffff0000u);
        float l2 = __uint_as_float(v2 << 16), g2 = __uint_as_float(v2 & 0xffff0000u);
        float l3 = __uint_as_float(v3 << 16), g3 = __uint_as_float(v3 & 0xffff0000u);
        float l4 = __uint_as_float(v4 << 16), g4 = __uint_as_float(v4 & 0xffff0000u);
        float l5 = __uint_as_float(v5 << 16), g5 = __uint_as_float(v5 & 0xffff0000u);
        float l6 = __uint_as_float(v6 << 16), g6 = __uint_as_float(v6 & 0xffff0000u);

        asx += l0 + w1 * l1 + w2 * l2 + w3 * l3 + w4 * l4 + w5 * l5 + w6 * l6;
        asy += g0 + w1 * g1 + w2 * g2 + w3 * g3 + w4 * g4 + w5 * g5 + w6 * g6;
        at  += c0 + w1 * c1 + w2 * c2 + w3 * c3 + w4 * c4 + w5 * c5 + w6 * c6;
        ae  += f0 + w1 * f1 + w2 * f2 + w3 * f3 + w4 * f4 + w5 * f5 + w6 * f6;
      }
    }

    float invc = (deg > 0) ? 1.0f / (float)deg : 0.0f;

    rb32[lane]       = pack2(asx * invc, asy * invc);   // k = 2*lane,2*lane+1
    rb[128 + lane]   = f2bf(at * invc);                 // k = 128+lane
    rb[192 + lane]   = f2bf(ae * invc);                 // k = 192+lane
    rb32[128 + lane] = pack2(hvf.x, hvf.y);             // k = 256+2*lane

    // wave-private LDS transpose, then node-major row write (768B contiguous)
    if (lane < 48) {
      short8 vv = *(const short8*)(rb + lane * 8);
      *(short8*)(Xb + (size_t)node * KDIM + lane * 8) = vv;
    }
  }
}

// ---------------- GEMM (100000 x 384) @ W''^T with fused GRU epilogue ----------------
// v12 structure (two barrier domains/CU) at K=384 (12 kt steps). Block = 512 thr /
// 8 waves, tile 4 mtiles x 512 out-cols. LDS = sA 2x4KB + sW 2x32KB = 72KB -> 2
// blocks/CU. Wave = 2 mtiles x 128 cols, ~125 VGPR.
__global__ __launch_bounds__(512, 4) void gemm_gru_kernel(
    const unsigned short* __restrict__ Xb,
    const unsigned short* __restrict__ Wb,
    const float* __restrict__ bb,
    const float* __restrict__ sj_r,
    const float* __restrict__ sj,
    float* __restrict__ out) {
  __shared__ __align__(16) unsigned short sA[2][2048];    // 2 x 4 KB : [mt4][512]
  __shared__ __align__(16) unsigned short sW[2][16384];   // 2 x 32 KB: [tt32][512]
  int wid = threadIdx.x >> 6, lane = threadIdx.x & 63;
  int mg = wid >> 2, cg = wid & 3;         // m-group 0..1, col-group 0..3
  int mbase = blockIdx.x * 4;
  int col16 = lane & 15, quad = lane >> 4;

  // staging sources: wave wid stages W slices tt = wid*4..wid*4+3;
  // waves 0..3 additionally stage A slice mt4 = wid.
  int mts = mbase + (wid & 3); if (mts >= MTILES) mts = MTILES - 1;
  const unsigned short* gA = Xb + (size_t)(mts * 16 + col16) * KDIM + quad * 8;
  const unsigned short* gB = Wb + (size_t)(wid * 4) * 12 * 512 + lane * 8;

#define STG(buf, kt)                                                          \
  {                                                                           \
    _Pragma("unroll")                                                         \
    for (int i = 0; i < 4; ++i)                                               \
      gload_lds16(gB + ((size_t)(i * 12 + (kt))) * 512, sW[buf] + (wid * 4 + i) * 512); \
    if (wid < 4) gload_lds16(gA + (kt) * 32, sA[buf] + (wid & 3) * 512);      \
  }

  f32x4 acc[2][8];                         // [mi][g*2+nt]
#pragma unroll
  for (int mi = 0; mi < 2; ++mi)
#pragma unroll
    for (int t8 = 0; t8 < 8; ++t8) acc[mi][t8] = (f32x4)0.0f;

  STG(0, 0)
  __syncthreads();

  for (int kt = 0; kt < 12; ++kt) {
    int cur = kt & 1;
    if (kt < 11) STG(cur ^ 1, kt + 1)
    short8 a[2], b[8];
#pragma unroll
    for (int mi = 0; mi < 2; ++mi)
      a[mi] = *(const short8*)(sA[cur] + (mg * 2 + mi) * 512 + lane * 8);
#pragma unroll
    for (int g = 0; g < 4; ++g)
#pragma unroll
      for (int nt = 0; nt < 2; ++nt)
        b[g * 2 + nt] = *(const short8*)(sW[cur] + (g * 8 + cg * 2 + nt) * 512 + lane * 8);
#pragma unroll
    for (int mi = 0; mi < 2; ++mi)
#pragma unroll
      for (int t8 = 0; t8 < 8; ++t8)
        acc[mi][t8] = __builtin_amdgcn_mfma_f32_16x16x32_bf16(a[mi], b[t8], acc[mi][t8], 0, 0, 0);
    __syncthreads();
  }

  // fused GRU epilogue: wave owns out cols (cg*2+nt)*16+col16, rows = its 2 mtiles
#pragma unroll
  for (int nt = 0; nt < 2; ++nt) {
    int cc = (cg * 2 + nt) * 16 + col16;
    float bbr = bb[cc], bbz = bb[128 + cc], bbn = bb[256 + cc], bbh = bb[384 + cc];
#pragma unroll
    for (int mi = 0; mi < 2; ++mi) {
      int mt = mbase + mg * 2 + mi;
      if (mt >= MTILES) continue;
#pragma unroll
      for (int r = 0; r < 4; ++r) {
        int row = mt * 16 + quad * 4 + r;
        float rp  = acc[mi][0 + nt][r] + bbr;   // gate r: t8 = 0*2+nt
        float zp  = acc[mi][2 + nt][r] + bbz;   // gate z: t8 = 1*2+nt
        float inp = acc[mi][4 + nt][r] + bbn;   // gate n: t8 = 2*2+nt
        float hnp = acc[mi][6 + nt][r] + bbh;   // gate h: t8 = 3*2+nt
        float rg = 1.0f / (1.0f + __expf(-rp));
        float zg = 1.0f / (1.0f + __expf(-zp));
        float ng = tanhf(inp + rg * hnp);
        float hv = (row < NUSERS) ? sj_r[(size_t)row * 128 + cc]
                                  : sj[(size_t)(row - NUSERS) * 128 + cc];
        out[(size_t)row * 128 + cc] = (1.0f - zg) * ng + zg * hv;
      }
    }
  }
}

// ---------------- fixup: deg==0 nodes (weight fold invalid there) --------------
// For deg==0: x = 0 -> gi = b_ih; gh = h@W_hh^T + b_hh. ~34 nodes expected.
__global__ __launch_bounds__(256) void fixup_kernel(
    const int* __restrict__ deg_j, const int* __restrict__ deg_i,
    const float* __restrict__ sj, const float* __restrict__ sj_r,
    const float* __restrict__ w_hh, const float* __restrict__ b_ih,
    const float* __restrict__ b_hh, float* __restrict__ out) {
  int w = blockIdx.x * 4 + (threadIdx.x >> 6), lane = threadIdx.x & 63;
  long base = (long)w * 64;
  if (base >= NTOT) return;
  int node = (int)base + lane;
  int dg = 1;
  if (node < NTOT) {
    bool user = node < NUSERS;
    dg = user ? deg_i[node] : deg_j[node - NUSERS];
  }
  unsigned long long zm = __ballot(dg == 0);
  while (zm) {
    int b = __ffsll((long long)zm) - 1; zm &= zm - 1;
    int zn = (int)base + b;
    bool zu = zn < NUSERS;
    const float* h = zu ? (sj_r + (size_t)zn * 128) : (sj + (size_t)(zn - NUSERS) * 128);
#pragma unroll
    for (int half = 0; half < 2; ++half) {
      int c = half * 64 + lane;
      float gr = 0.f, gz = 0.f, gn = 0.f;
      for (int k = 0; k < 128; ++k) {
        float hk = h[k];
        gr += w_hh[(size_t)c * 128 + k] * hk;
        gz += w_hh[(size_t)(128 + c) * 128 + k] * hk;
        gn += w_hh[(size_t)(256 + c) * 128 + k] * hk;
      }
      float rg = 1.0f / (1.0f + __expf(-(b_ih[c] + b_hh[c] + gr)));
      float zg = 1.0f / (1.0f + __expf(-(b_ih[128 + c] + b_hh[128 + c] + gz)));
      float ng = tanhf(b_ih[256 + c] + rg * (b_hh[256 + c] + gn));
      out[(size_t)zn * 128 + c] = (1.0f - zg) * ng + zg * h[c];
    }
  }
}

extern "C" void kernel_launch(void* const* d_in, const int* in_sizes, int n_in,
                              void* d_out, int out_size, void* d_ws, size_t ws_size,
                              hipStream_t stream) {
  const float* si   = (const float*)d_in[0];
  const float* sj   = (const float*)d_in[1];
  const float* si_r = (const float*)d_in[2];
  const float* sj_r = (const float*)d_in[3];
  const float* t    = (const float*)d_in[4];
  const float* t_r  = (const float*)d_in[5];
  const float* e    = (const float*)d_in[6];
  const float* e_r  = (const float*)d_in[7];
  const float* w_ih = (const float*)d_in[8];
  const float* w_hh = (const float*)d_in[9];
  const float* b_ih = (const float*)d_in[10];
  const float* b_hh = (const float*)d_in[11];
  const int* src_g  = (const int*)d_in[12];
  const int* dst_g  = (const int*)d_in[13];
  const int* src_gr = (const int*)d_in[14];
  const int* dst_gr = (const int*)d_in[15];
  int E = in_sizes[4];

  // workspace layout (16B-aligned head first)
  unsigned short* Xb = (unsigned short*)d_ws;          // NTOT*384 shorts (76.8 MB), node-major
  unsigned short* Wb = Xb + (size_t)NTOT * KDIM;       // 512*384 = 196608 shorts
  float* bb   = (float*)(Wb + 196608);                 // 512
  int* deg_j  = (int*)(bb + 512);                      // 50000  (memset target, with deg_i)
  int* deg_i  = deg_j + NNODE;                         // 50000
  int* rs_j   = deg_i + NNODE;                         // 50000
  int* rs_i   = rs_j + NNODE;                          // 50000
  int* cur_j  = rs_i + NNODE;                          // 50000
  int* cur_i  = cur_j + NNODE;                         // 50000
  int* csum   = cur_i + NNODE;                         // 2*NCHUNK
  int* coff   = csum + 2 * NCHUNK;                     // 2*NCHUNK (ends 16B-aligned)
  int4* recP_j = (int4*)(coff + 2 * NCHUNK);           // E int4
  int4* recP_i = recP_j + E;                           // E int4
  unsigned short* si_b  = (unsigned short*)(recP_i + E);  // 6.4M shorts (12.8 MB)
  unsigned short* sir_b = si_b + 6400000;                 // 6.4M shorts (12.8 MB)

  hipMemsetAsync(deg_j, 0, 2 * NNODE * sizeof(int), stream);

  int hblks = (2 * E + 255) / 256;
  prep_kernel<<<PBLK + CBLK + hblks, 256, 0, stream>>>(
      w_ih, w_hh, b_ih, b_hh, Wb, bb,
      si, si_r, si_b, sir_b,
      dst_g, dst_gr, deg_j, deg_i, E);

  chunksum_kernel<<<2 * NCHUNK, 256, 0, stream>>>(deg_j, deg_i, csum);
  chunkscan_kernel<<<2, 256, 0, stream>>>(csum, coff);
  localscan_kernel<<<2 * NCHUNK, 256, 0, stream>>>(deg_j, deg_i, coff, rs_j, cur_j, rs_i, cur_i);

  fill_kernel<<<hblks, 256, 0, stream>>>(src_g, dst_g, t, src_gr, dst_gr, t_r,
                                         cur_j, cur_i, recP_j, recP_i, E);

  gather_kernel<<<NWAVES / 4, 256, 0, stream>>>(si_b, sir_b, sj, sj_r, e, e_r,
                                                rs_j, rs_i, deg_j, deg_i,
                                                recP_j, recP_i, Xb);

  float* out = (float*)d_out;
  gemm_gru_kernel<<<(MTILES + 3) / 4, 512, 0, stream>>>(Xb, Wb, bb, sj_r, sj, out);
  fixup_kernel<<<391, 256, 0, stream>>>(deg_j, deg_i, sj, sj_r, w_hh, b_ih, b_hh, out);
}

// Round 15
// 558.335 us; speedup vs baseline: 1.1439x; 1.0168x over previous
//
#include <hip/hip_runtime.h>
#include <math.h>

#define NUSERS 50000
#define NITEMS 50000
#define NTOT   100000
#define NNODE  50000      // per direction
#define NCHUNK 196        // ceil(50000/256)
#define MTILES 6250       // 100000/16 row tiles
#define KDIM   384        // folded K: [mean_src 128 | tenc 64 | ef 64 | h 128]
#define NWAVES 16384      // gather: 4096 blocks x 4 waves; 2x oversubscribed so
                          // finished blocks retire and queued blocks backfill the tail
#define PBLK   768        // prep: pack_w blocks (512*384/256)
#define CBLK   6250       // prep: cast_mem blocks

typedef __attribute__((ext_vector_type(4))) float f32x4;
typedef __attribute__((ext_vector_type(8))) short short8;
typedef unsigned int u32;

#define AS1 __attribute__((address_space(1)))
#define AS3 __attribute__((address_space(3)))

static __device__ __forceinline__ unsigned short f2bf(float f) {
  unsigned int u = __float_as_uint(f);
  u += 0x7fffu + ((u >> 16) & 1u);
  return (unsigned short)(u >> 16);
}

static __device__ __forceinline__ u32 pack2(float x, float y) {
  return (u32)f2bf(x) | ((u32)f2bf(y) << 16);
}

static __device__ __forceinline__ void gload_lds16(const void* g, void* l) {
  __builtin_amdgcn_global_load_lds((const AS1 u32*)g, (AS3 u32*)l, 16, 0, 0);
}

// ---------------- prep: pack_w + cast_mem + hist fused (independent work) -------
// blocks [0,PBLK): pack W'' (512 gates x 384 k) into MFMA B-fragment order.
//   k<128: W_ih src cols. 128<=k<256: W_ih cols 256:384 (tenc+ef). k>=256 (c):
//     g<256 (rz):   W_ih[g,128+c] + W_hh[g,c]   (dst-mean == h folded)
//     256<=g<384:   W_ih[g,128+c]               (i_n dst part; deg==0 fixed up)
//     g>=384 (h_n): W_hh[g-128,c]
// blocks [PBLK,PBLK+CBLK): bf16 pre-cast of si/si_r (gathered arrays).
// blocks [PBLK+CBLK,...): degree histogram (atomics on zeroed deg arrays).
__global__ void prep_kernel(const float* __restrict__ w_ih,
                            const float* __restrict__ w_hh,
                            const float* __restrict__ b_ih,
                            const float* __restrict__ b_hh,
                            unsigned short* __restrict__ Wb,
                            float* __restrict__ bb,
                            const float* __restrict__ si,
                            const float* __restrict__ si_r,
                            unsigned short* __restrict__ si_b,
                            unsigned short* __restrict__ sir_b,
                            const int* __restrict__ dst_g,
                            const int* __restrict__ dst_gr,
                            int* __restrict__ deg_j, int* __restrict__ deg_i,
                            int E) {
  int blk = blockIdx.x;
  if (blk < PBLK) {
    int idx = blk * 256 + threadIdx.x;              // 0 .. 512*384-1
    int j = idx & 7, l = (idx >> 3) & 63, ktt = idx >> 9;   // ktt = tt*12 + kt
    int kt = ktt % 12, tt = ktt / 12;
    int g = tt * 16 + (l & 15);
    int k = kt * 32 + (l >> 4) * 8 + j;
    float v;
    if (k < 128) {
      v = (g < 384) ? w_ih[g * 384 + k] : 0.0f;
    } else if (k < 256) {
      v = (g < 384) ? w_ih[g * 384 + 128 + k] : 0.0f;   // col 256+(k-128)
    } else {
      int c = k - 256;
      if (g < 256)      v = w_ih[g * 384 + 128 + c] + w_hh[g * 128 + c];
      else if (g < 384) v = w_ih[g * 384 + 128 + c];
      else              v = w_hh[(size_t)(g - 128) * 128 + c];
    }
    Wb[idx] = f2bf(v);
    if (idx < 512) {
      float b = (idx < 256) ? (b_ih[idx] + b_hh[idx])
              : (idx < 384) ? b_ih[idx]
                            : b_hh[idx - 128];
      bb[idx] = b;
    }
  } else if (blk < PBLK + CBLK) {
    int i = (blk - PBLK) * 256 + threadIdx.x;       // 0 .. 1,599,999 (8 floats each)
    const float* src; unsigned short* dst; int off;
    if (i < 800000) { src = si;   dst = si_b;  off = i; }
    else            { src = si_r; dst = sir_b; off = i - 800000; }
    const f32x4* p = (const f32x4*)(src + (size_t)off * 8);
    f32x4 a = p[0], b = p[1];
    short8 o;
    o[0] = f2bf(a[0]); o[1] = f2bf(a[1]); o[2] = f2bf(a[2]); o[3] = f2bf(a[3]);
    o[4] = f2bf(b[0]); o[5] = f2bf(b[1]); o[6] = f2bf(b[2]); o[7] = f2bf(b[3]);
    *(short8*)(dst + (size_t)off * 8) = o;
  } else {
    int i = (blk - PBLK - CBLK) * 256 + threadIdx.x;
    if (i < E) atomicAdd(&deg_j[dst_g[i]], 1);
    else if (i < 2 * E) atomicAdd(&deg_i[dst_gr[i - E]], 1);
  }
}

// ---------------- CSR scan: proven 3-kernel chain (round-12) -----------------
__global__ void chunksum_kernel(const int* __restrict__ deg_j,
                                const int* __restrict__ deg_i,
                                int* __restrict__ csum) {
  int c = blockIdx.x;                    // 0..2*NCHUNK-1
  const int* deg = (c < NCHUNK) ? deg_j : deg_i;
  int cc = (c < NCHUNK) ? c : c - NCHUNK;
  int t = threadIdx.x;
  int idx = cc * 256 + t;
  int v = (idx < NNODE) ? deg[idx] : 0;
  for (int off = 32; off; off >>= 1) v += __shfl_down(v, off, 64);
  __shared__ int wsum[4];
  if ((t & 63) == 0) wsum[t >> 6] = v;
  __syncthreads();
  if (t == 0) csum[c] = wsum[0] + wsum[1] + wsum[2] + wsum[3];
}

__global__ void chunkscan_kernel(const int* __restrict__ csum, int* __restrict__ coff) {
  int d = blockIdx.x;                    // 0 or 1
  const int* cs = csum + d * NCHUNK;
  int* co = coff + d * NCHUNK;
  int t = threadIdx.x, lane = t & 63, w = t >> 6;
  int v = (t < NCHUNK) ? cs[t] : 0;
  int x = v;
  for (int off = 1; off < 64; off <<= 1) {
    int y = __shfl_up(x, off, 64);
    if (lane >= off) x += y;
  }
  __shared__ int wt[4];
  if (lane == 63) wt[w] = x;
  __syncthreads();
  int add = 0;
  for (int k = 0; k < 4; ++k) if (k < w) add += wt[k];
  if (t < NCHUNK) co[t] = add + x - v;   // exclusive prefix
}

__global__ void localscan_kernel(const int* __restrict__ deg_j,
                                 const int* __restrict__ deg_i,
                                 const int* __restrict__ coff,
                                 int* __restrict__ rs_j, int* __restrict__ cur_j,
                                 int* __restrict__ rs_i, int* __restrict__ cur_i) {
  int c = blockIdx.x;
  bool dj = c < NCHUNK;
  const int* deg = dj ? deg_j : deg_i;
  int cc = dj ? c : c - NCHUNK;
  int* rs = dj ? rs_j : rs_i;
  int* cur = dj ? cur_j : cur_i;
  int base = coff[c];
  int t = threadIdx.x, lane = t & 63, w = t >> 6;
  int idx = cc * 256 + t;
  int v = (idx < NNODE) ? deg[idx] : 0;
  int x = v;
  for (int off = 1; off < 64; off <<= 1) {
    int y = __shfl_up(x, off, 64);
    if (lane >= off) x += y;
  }
  __shared__ int wt[4];
  if (lane == 63) wt[w] = x;
  __syncthreads();
  int add = 0;
  for (int k = 0; k < 4; ++k) if (k < w) add += wt[k];
  int ex = base + add + x - v;
  if (idx < NNODE) { rs[idx] = ex; cur[idx] = ex; }
}

// fill: one 16B record per edge: (src, eid, ts_bits, 0)
__global__ void fill_kernel(const int* __restrict__ src_g, const int* __restrict__ dst_g,
                            const float* __restrict__ t,
                            const int* __restrict__ src_gr, const int* __restrict__ dst_gr,
                            const float* __restrict__ t_r,
                            int* __restrict__ cur_j, int* __restrict__ cur_i,
                            int4* __restrict__ recP_j, int4* __restrict__ recP_i,
                            int E) {
  int i = blockIdx.x * 256 + threadIdx.x;
  if (i < E) {
    int pos = atomicAdd(&cur_j[dst_g[i]], 1);
    recP_j[pos] = make_int4(src_g[i], i, __float_as_int(t[i]), 0);
  } else if (i < 2 * E) {
    int k = i - E;
    int pos = atomicAdd(&cur_i[dst_gr[k]], 1);
    recP_i[pos] = make_int4(src_gr[k], k, __float_as_int(t_r[k]), 0);
  }
}

// ---------------- gather: mean-message, write X row NODE-MAJOR (768B) ----------
// packed k layout: [0,128)=mean src_mem, [128,192)=mean tenc, [192,256)=mean ef,
// [256,384)=h. (h*(deg>0) channel folded into packed weights; deg==0 fixed up.)
__global__ __launch_bounds__(256) void gather_kernel(
    const unsigned short* __restrict__ si_b, const unsigned short* __restrict__ sir_b,
    const float* __restrict__ sj, const float* __restrict__ sj_r,
    const float* __restrict__ e, const float* __restrict__ e_r,
    const int* __restrict__ rs_j, const int* __restrict__ rs_i,
    const int* __restrict__ deg_j, const int* __restrict__ deg_i,
    const int4* __restrict__ recP_j, const int4* __restrict__ recP_i,
    unsigned short* __restrict__ Xb) {
  __shared__ __align__(16) unsigned short rowbuf[4][384];
  int wid = threadIdx.x >> 6, lane = threadIdx.x & 63;
  int gwave = blockIdx.x * 4 + wid;                // 0..NWAVES-1
  // freq[lane] = 10^(-9*lane/63) = exp(-lane * 9/63 * ln 10)
  float freq = __expf((float)lane * -0.3289407276f);
  unsigned short* rb = rowbuf[wid];
  u32* rb32 = (u32*)rb;

  for (int node = gwave; node < NTOT; node += NWAVES) {
    bool user = node < NUSERS;
    int idx = user ? node : node - NUSERS;
    const unsigned short* smem = user ? sir_b : si_b;   // bf16 rows, 128 shorts
    const float* h  = user ? sj_r : sj;
    const float* ef = user ? e_r : e;
    int start = __builtin_amdgcn_readfirstlane((user ? rs_i : rs_j)[idx]);
    int deg   = __builtin_amdgcn_readfirstlane((user ? deg_i : deg_j)[idx]);
    const int4* rec = user ? recP_i : recP_j;

    // h row: issue early, consumed only in the epilogue
    float2 hvf = *(const float2*)(h + (size_t)idx * 128 + 2 * lane);

    float asx = 0.f, asy = 0.f;   // mean src_mem, k = 2*lane, 2*lane+1
    float at  = 0.f;              // tenc, k = 128+lane
    float ae  = 0.f;              // edge feat, k = 192+lane

    for (int base = 0; base < deg; base += 64) {
      int nn = deg - base; if (nn > 64) nn = 64;
      // cooperative record load: lane l holds record base+l (clamped)
      int cl = (lane < nn) ? base + lane : base + nn - 1;
      int4 r = rec[start + cl];
      int full = nn & ~7;
      // ---- unclamped full rounds: no weights, no dup loads ----
      for (int j0 = 0; j0 < full; j0 += 8) {
        int s0 = __builtin_amdgcn_readlane(r.x, j0 + 0), e0 = __builtin_amdgcn_readlane(r.y, j0 + 0);
        int s1 = __builtin_amdgcn_readlane(r.x, j0 + 1), e1 = __builtin_amdgcn_readlane(r.y, j0 + 1);
        int s2 = __builtin_amdgcn_readlane(r.x, j0 + 2), e2 = __builtin_amdgcn_readlane(r.y, j0 + 2);
        int s3 = __builtin_amdgcn_readlane(r.x, j0 + 3), e3 = __builtin_amdgcn_readlane(r.y, j0 + 3);
        int s4 = __builtin_amdgcn_readlane(r.x, j0 + 4), e4 = __builtin_amdgcn_readlane(r.y, j0 + 4);
        int s5 = __builtin_amdgcn_readlane(r.x, j0 + 5), e5 = __builtin_amdgcn_readlane(r.y, j0 + 5);
        int s6 = __builtin_amdgcn_readlane(r.x, j0 + 6), e6 = __builtin_amdgcn_readlane(r.y, j0 + 6);
        int s7 = __builtin_amdgcn_readlane(r.x, j0 + 7), e7 = __builtin_amdgcn_readlane(r.y, j0 + 7);

        u32 v0 = *(const u32*)(smem + ((size_t)s0 << 7) + 2 * lane);
        u32 v1 = *(const u32*)(smem + ((size_t)s1 << 7) + 2 * lane);
        u32 v2 = *(const u32*)(smem + ((size_t)s2 << 7) + 2 * lane);
        u32 v3 = *(const u32*)(smem + ((size_t)s3 << 7) + 2 * lane);
        u32 v4 = *(const u32*)(smem + ((size_t)s4 << 7) + 2 * lane);
        u32 v5 = *(const u32*)(smem + ((size_t)s5 << 7) + 2 * lane);
        u32 v6 = *(const u32*)(smem + ((size_t)s6 << 7) + 2 * lane);
        u32 v7 = *(const u32*)(smem + ((size_t)s7 << 7) + 2 * lane);
        float f0 = ef[((size_t)e0 << 6) + lane];
        float f1 = ef[((size_t)e1 << 6) + lane];
        float f2 = ef[((size_t)e2 << 6) + lane];
        float f3 = ef[((size_t)e3 << 6) + lane];
        float f4 = ef[((size_t)e4 << 6) + lane];
        float f5 = ef[((size_t)e5 << 6) + lane];
        float f6 = ef[((size_t)e6 << 6) + lane];
        float f7 = ef[((size_t)e7 << 6) + lane];

        float c0 = __cosf(__int_as_float(__builtin_amdgcn_readlane(r.z, j0 + 0)) * freq);
        float c1 = __cosf(__int_as_float(__builtin_amdgcn_readlane(r.z, j0 + 1)) * freq);
        float c2 = __cosf(__int_as_float(__builtin_amdgcn_readlane(r.z, j0 + 2)) * freq);
        float c3 = __cosf(__int_as_float(__builtin_amdgcn_readlane(r.z, j0 + 3)) * freq);
        float c4 = __cosf(__int_as_float(__builtin_amdgcn_readlane(r.z, j0 + 4)) * freq);
        float c5 = __cosf(__int_as_float(__builtin_amdgcn_readlane(r.z, j0 + 5)) * freq);
        float c6 = __cosf(__int_as_float(__builtin_amdgcn_readlane(r.z, j0 + 6)) * freq);
        float c7 = __cosf(__int_as_float(__builtin_amdgcn_readlane(r.z, j0 + 7)) * freq);

        float l0 = __uint_as_float(v0 << 16), g0 = __uint_as_float(v0 & 0xffff0000u);
        float l1 = __uint_as_float(v1 << 16), g1 = __uint_as_float(v1 & 0xffff0000u);
        float l2 = __uint_as_float(v2 << 16), g2 = __uint_as_float(v2 & 0xffff0000u);
        float l3 = __uint_as_float(v3 << 16), g3 = __uint_as_float(v3 & 0xffff0000u);
        float l4 = __uint_as_float(v4 << 16), g4 = __uint_as_float(v4 & 0xffff0000u);
        float l5 = __uint_as_float(v5 << 16), g5 = __uint_as_float(v5 & 0xffff0000u);
        float l6 = __uint_as_float(v6 << 16), g6 = __uint_as_float(v6 & 0xffff0000u);
        float l7 = __uint_as_float(v7 << 16), g7 = __uint_as_float(v7 & 0xffff0000u);

        asx += ((l0 + l1) + (l2 + l3)) + ((l4 + l5) + (l6 + l7));
        asy += ((g0 + g1) + (g2 + g3)) + ((g4 + g5) + (g6 + g7));
        at  += ((c0 + c1) + (c2 + c3)) + ((c4 + c5) + (c6 + c7));
        ae  += ((f0 + f1) + (f2 + f3)) + ((f4 + f5) + (f6 + f7));
      }
      // ---- clamped tail (1..7 real edges) ----
      if (full < nn) {
        int j0 = full;
        int j1 = (j0 + 1 < nn) ? j0 + 1 : nn - 1;
        int j2 = (j0 + 2 < nn) ? j0 + 2 : nn - 1;
        int j3 = (j0 + 3 < nn) ? j0 + 3 : nn - 1;
        int j4 = (j0 + 4 < nn) ? j0 + 4 : nn - 1;
        int j5 = (j0 + 5 < nn) ? j0 + 5 : nn - 1;
        int j6 = (j0 + 6 < nn) ? j0 + 6 : nn - 1;
        float w1 = (j0 + 1 < nn) ? 1.0f : 0.0f;
        float w2 = (j0 + 2 < nn) ? 1.0f : 0.0f;
        float w3 = (j0 + 3 < nn) ? 1.0f : 0.0f;
        float w4 = (j0 + 4 < nn) ? 1.0f : 0.0f;
        float w5 = (j0 + 5 < nn) ? 1.0f : 0.0f;
        float w6 = (j0 + 6 < nn) ? 1.0f : 0.0f;

        int s0 = __builtin_amdgcn_readlane(r.x, j0), e0 = __builtin_amdgcn_readlane(r.y, j0);
        int s1 = __builtin_amdgcn_readlane(r.x, j1), e1 = __builtin_amdgcn_readlane(r.y, j1);
        int s2 = __builtin_amdgcn_readlane(r.x, j2), e2 = __builtin_amdgcn_readlane(r.y, j2);
        int s3 = __builtin_amdgcn_readlane(r.x, j3), e3 = __builtin_amdgcn_readlane(r.y, j3);
        int s4 = __builtin_amdgcn_readlane(r.x, j4), e4 = __builtin_amdgcn_readlane(r.y, j4);
        int s5 = __builtin_amdgcn_readlane(r.x, j5), e5 = __builtin_amdgcn_readlane(r.y, j5);
        int s6 = __builtin_amdgcn_readlane(r.x, j6), e6 = __builtin_amdgcn_readlane(r.y, j6);

        u32 v0 = *(const u32*)(smem + ((size_t)s0 << 7) + 2 * lane);
        u32 v1 = *(const u32*)(smem + ((size_t)s1 << 7) + 2 * lane);
        u32 v2 = *(const u32*)(smem + ((size_t)s2 << 7) + 2 * lane);
        u32 v3 = *(const u32*)(smem + ((size_t)s3 << 7) + 2 * lane);
        u32 v4 = *(const u32*)(smem + ((size_t)s4 << 7) + 2 * lane);
        u32 v5 = *(const u32*)(smem + ((size_t)s5 << 7) + 2 * lane);
        u32 v6 = *(const u32*)(smem + ((size_t)s6 << 7) + 2 * lane);
        float f0 = ef[((size_t)e0 << 6) + lane];
        float f1 = ef[((size_t)e1 << 6) + lane];
        float f2 = ef[((size_t)e2 << 6) + lane];
        float f3 = ef[((size_t)e3 << 6) + lane];
        float f4 = ef[((size_t)e4 << 6) + lane];
        float f5 = ef[((size_t)e5 << 6) + lane];
        float f6 = ef[((size_t)e6 << 6) + lane];

        float c0 = __cosf(__int_as_float(__builtin_amdgcn_readlane(r.z, j0)) * freq);
        float c1 = __cosf(__int_as_float(__builtin_amdgcn_readlane(r.z, j1)) * freq);
        float c2 = __cosf(__int_as_float(__builtin_amdgcn_readlane(r.z, j2)) * freq);
        float c3 = __cosf(__int_as_float(__builtin_amdgcn_readlane(r.z, j3)) * freq);
        float c4 = __cosf(__int_as_float(__builtin_amdgcn_readlane(r.z, j4)) * freq);
        float c5 = __cosf(__int_as_float(__builtin_amdgcn_readlane(r.z, j5)) * freq);
        float c6 = __cosf(__int_as_float(__builtin_amdgcn_readlane(r.z, j6)) * freq);

        float l0 = __uint_as_float(v0 << 16), g0 = __uint_as_float(v0 & 0xffff0000u);
        float l1 = __uint_as_float(v1 << 16), g1 = __uint_as_float(v1 & 0xffff0000u);
        float l2 = __uint_as_float(v2 << 16), g2 = __uint_as_float(v2 & 0xffff0000u);
        float l3 = __uint_as_float(v3 << 16), g3 = __uint_as_float(v3 & 0xffff0000u);
        float l4 = __uint_as_float(v4 << 16), g4 = __uint_as_float(v4 & 0xffff0000u);
        float l5 = __uint_as_float(v5 << 16), g5 = __uint_as_float(v5 & 0xffff0000u);
        float l6 = __uint_as_float(v6 << 16), g6 = __uint_as_float(v6 & 0xffff0000u);

        asx += l0 + w1 * l1 + w2 * l2 + w3 * l3 + w4 * l4 + w5 * l5 + w6 * l6;
        asy += g0 + w1 * g1 + w2 * g2 + w3 * g3 + w4 * g4 + w5 * g5 + w6 * g6;
        at  += c0 + w1 * c1 + w2 * c2 + w3 * c3 + w4 * c4 + w5 * c5 + w6 * c6;
        ae  += f0 + w1 * f1 + w2 * f2 + w3 * f3 + w4 * f4 + w5 * f5 + w6 * f6;
      }
    }

    float invc = (deg > 0) ? 1.0f / (float)deg : 0.0f;

    rb32[lane]       = pack2(asx * invc, asy * invc);   // k = 2*lane,2*lane+1
    rb[128 + lane]   = f2bf(at * invc);                 // k = 128+lane
    rb[192 + lane]   = f2bf(ae * invc);                 // k = 192+lane
    rb32[128 + lane] = pack2(hvf.x, hvf.y);             // k = 256+2*lane

    // wave-private LDS transpose, then node-major row write (768B contiguous)
    if (lane < 48) {
      short8 vv = *(const short8*)(rb + lane * 8);
      *(short8*)(Xb + (size_t)node * KDIM + lane * 8) = vv;
    }
  }
}

// ---------------- GEMM (100000 x 384) @ W''^T with fused GRU epilogue ----------------
// v12 structure (two barrier domains/CU) at K=384 (12 kt steps). Block = 512 thr /
// 8 waves, tile 4 mtiles x 512 out-cols. LDS = sA 2x4KB + sW 2x32KB = 72KB -> 2
// blocks/CU. Wave = 2 mtiles x 128 cols, ~125 VGPR.
__global__ __launch_bounds__(512, 4) void gemm_gru_kernel(
    const unsigned short* __restrict__ Xb,
    const unsigned short* __restrict__ Wb,
    const float* __restrict__ bb,
    const float* __restrict__ sj_r,
    const float* __restrict__ sj,
    float* __restrict__ out) {
  __shared__ __align__(16) unsigned short sA[2][2048];    // 2 x 4 KB : [mt4][512]
  __shared__ __align__(16) unsigned short sW[2][16384];   // 2 x 32 KB: [tt32][512]
  int wid = threadIdx.x >> 6, lane = threadIdx.x & 63;
  int mg = wid >> 2, cg = wid & 3;         // m-group 0..1, col-group 0..3
  int mbase = blockIdx.x * 4;
  int col16 = lane & 15, quad = lane >> 4;

  // staging sources: wave wid stages W slices tt = wid*4..wid*4+3;
  // waves 0..3 additionally stage A slice mt4 = wid.
  int mts = mbase + (wid & 3); if (mts >= MTILES) mts = MTILES - 1;
  const unsigned short* gA = Xb + (size_t)(mts * 16 + col16) * KDIM + quad * 8;
  const unsigned short* gB = Wb + (size_t)(wid * 4) * 12 * 512 + lane * 8;

#define STG(buf, kt)                                                          \
  {                                                                           \
    _Pragma("unroll")                                                         \
    for (int i = 0; i < 4; ++i)                                               \
      gload_lds16(gB + ((size_t)(i * 12 + (kt))) * 512, sW[buf] + (wid * 4 + i) * 512); \
    if (wid < 4) gload_lds16(gA + (kt) * 32, sA[buf] + (wid & 3) * 512);      \
  }

  f32x4 acc[2][8];                         // [mi][g*2+nt]
#pragma unroll
  for (int mi = 0; mi < 2; ++mi)
#pragma unroll
    for (int t8 = 0; t8 < 8; ++t8) acc[mi][t8] = (f32x4)0.0f;

  STG(0, 0)
  __syncthreads();

  for (int kt = 0; kt < 12; ++kt) {
    int cur = kt & 1;
    if (kt < 11) STG(cur ^ 1, kt + 1)
    short8 a[2], b[8];
#pragma unroll
    for (int mi = 0; mi < 2; ++mi)
      a[mi] = *(const short8*)(sA[cur] + (mg * 2 + mi) * 512 + lane * 8);
#pragma unroll
    for (int g = 0; g < 4; ++g)
#pragma unroll
      for (int nt = 0; nt < 2; ++nt)
        b[g * 2 + nt] = *(const short8*)(sW[cur] + (g * 8 + cg * 2 + nt) * 512 + lane * 8);
#pragma unroll
    for (int mi = 0; mi < 2; ++mi)
#pragma unroll
      for (int t8 = 0; t8 < 8; ++t8)
        acc[mi][t8] = __builtin_amdgcn_mfma_f32_16x16x32_bf16(a[mi], b[t8], acc[mi][t8], 0, 0, 0);
    __syncthreads();
  }

  // fused GRU epilogue: wave owns out cols (cg*2+nt)*16+col16, rows = its 2 mtiles
#pragma unroll
  for (int nt = 0; nt < 2; ++nt) {
    int cc = (cg * 2 + nt) * 16 + col16;
    float bbr = bb[cc], bbz = bb[128 + cc], bbn = bb[256 + cc], bbh = bb[384 + cc];
#pragma unroll
    for (int mi = 0; mi < 2; ++mi) {
      int mt = mbase + mg * 2 + mi;
      if (mt >= MTILES) continue;
#pragma unroll
      for (int r = 0; r < 4; ++r) {
        int row = mt * 16 + quad * 4 + r;
        float rp  = acc[mi][0 + nt][r] + bbr;   // gate r: t8 = 0*2+nt
        float zp  = acc[mi][2 + nt][r] + bbz;   // gate z: t8 = 1*2+nt
        float inp = acc[mi][4 + nt][r] + bbn;   // gate n: t8 = 2*2+nt
        float hnp = acc[mi][6 + nt][r] + bbh;   // gate h: t8 = 3*2+nt
        float rg = 1.0f / (1.0f + __expf(-rp));
        float zg = 1.0f / (1.0f + __expf(-zp));
        float ng = tanhf(inp + rg * hnp);
        float hv = (row < NUSERS) ? sj_r[(size_t)row * 128 + cc]
                                  : sj[(size_t)(row - NUSERS) * 128 + cc];
        out[(size_t)row * 128 + cc] = (1.0f - zg) * ng + zg * hv;
      }
    }
  }
}

// ---------------- fixup: deg==0 nodes (weight fold invalid there) --------------
// For deg==0: x = 0 -> gi = b_ih; gh = h@W_hh^T + b_hh. ~34 nodes expected.
__global__ __launch_bounds__(256) void fixup_kernel(
    const int* __restrict__ deg_j, const int* __restrict__ deg_i,
    const float* __restrict__ sj, const float* __restrict__ sj_r,
    const float* __restrict__ w_hh, const float* __restrict__ b_ih,
    const float* __restrict__ b_hh, float* __restrict__ out) {
  int w = blockIdx.x * 4 + (threadIdx.x >> 6), lane = threadIdx.x & 63;
  long base = (long)w * 64;
  if (base >= NTOT) return;
  int node = (int)base + lane;
  int dg = 1;
  if (node < NTOT) {
    bool user = node < NUSERS;
    dg = user ? deg_i[node] : deg_j[node - NUSERS];
  }
  unsigned long long zm = __ballot(dg == 0);
  while (zm) {
    int b = __ffsll((long long)zm) - 1; zm &= zm - 1;
    int zn = (int)base + b;
    bool zu = zn < NUSERS;
    const float* h = zu ? (sj_r + (size_t)zn * 128) : (sj + (size_t)(zn - NUSERS) * 128);
#pragma unroll
    for (int half = 0; half < 2; ++half) {
      int c = half * 64 + lane;
      float gr = 0.f, gz = 0.f, gn = 0.f;
      for (int k = 0; k < 128; ++k) {
        float hk = h[k];
        gr += w_hh[(size_t)c * 128 + k] * hk;
        gz += w_hh[(size_t)(128 + c) * 128 + k] * hk;
        gn += w_hh[(size_t)(256 + c) * 128 + k] * hk;
      }
      float rg = 1.0f / (1.0f + __expf(-(b_ih[c] + b_hh[c] + gr)));
      float zg = 1.0f / (1.0f + __expf(-(b_ih[128 + c] + b_hh[128 + c] + gz)));
      float ng = tanhf(b_ih[256 + c] + rg * (b_hh[256 + c] + gn));
      out[(size_t)zn * 128 + c] = (1.0f - zg) * ng + zg * h[c];
    }
  }
}

extern "C" void kernel_launch(void* const* d_in, const int* in_sizes, int n_in,
                              void* d_out, int out_size, void* d_ws, size_t ws_size,
                              hipStream_t stream) {
  const float* si   = (const float*)d_in[0];
  const float* sj   = (const float*)d_in[1];
  const float* si_r = (const float*)d_in[2];
  const float* sj_r = (const float*)d_in[3];
  const float* t    = (const float*)d_in[4];
  const float* t_r  = (const float*)d_in[5];
  const float* e    = (const float*)d_in[6];
  const float* e_r  = (const float*)d_in[7];
  const float* w_ih = (const float*)d_in[8];
  const float* w_hh = (const float*)d_in[9];
  const float* b_ih = (const float*)d_in[10];
  const float* b_hh = (const float*)d_in[11];
  const int* src_g  = (const int*)d_in[12];
  const int* dst_g  = (const int*)d_in[13];
  const int* src_gr = (const int*)d_in[14];
  const int* dst_gr = (const int*)d_in[15];
  int E = in_sizes[4];

  // workspace layout (16B-aligned head first)
  unsigned short* Xb = (unsigned short*)d_ws;          // NTOT*384 shorts (76.8 MB), node-major
  unsigned short* Wb = Xb + (size_t)NTOT * KDIM;       // 512*384 = 196608 shorts
  float* bb   = (float*)(Wb + 196608);                 // 512
  int* deg_j  = (int*)(bb + 512);                      // 50000  (memset target, with deg_i)
  int* deg_i  = deg_j + NNODE;                         // 50000
  int* rs_j   = deg_i + NNODE;                         // 50000
  int* rs_i   = rs_j + NNODE;                          // 50000
  int* cur_j  = rs_i + NNODE;                          // 50000
  int* cur_i  = cur_j + NNODE;                         // 50000
  int* csum   = cur_i + NNODE;                         // 2*NCHUNK
  int* coff   = csum + 2 * NCHUNK;                     // 2*NCHUNK (ends 16B-aligned)
  int4* recP_j = (int4*)(coff + 2 * NCHUNK);           // E int4
  int4* recP_i = recP_j + E;                           // E int4
  unsigned short* si_b  = (unsigned short*)(recP_i + E);  // 6.4M shorts (12.8 MB)
  unsigned short* sir_b = si_b + 6400000;                 // 6.4M shorts (12.8 MB)

  hipMemsetAsync(deg_j, 0, 2 * NNODE * sizeof(int), stream);

  int hblks = (2 * E + 255) / 256;
  prep_kernel<<<PBLK + CBLK + hblks, 256, 0, stream>>>(
      w_ih, w_hh, b_ih, b_hh, Wb, bb,
      si, si_r, si_b, sir_b,
      dst_g, dst_gr, deg_j, deg_i, E);

  chunksum_kernel<<<2 * NCHUNK, 256, 0, stream>>>(deg_j, deg_i, csum);
  chunkscan_kernel<<<2, 256, 0, stream>>>(csum, coff);
  localscan_kernel<<<2 * NCHUNK, 256, 0, stream>>>(deg_j, deg_i, coff, rs_j, cur_j, rs_i, cur_i);

  fill_kernel<<<hblks, 256, 0, stream>>>(src_g, dst_g, t, src_gr, dst_gr, t_r,
                                         cur_j, cur_i, recP_j, recP_i, E);

  gather_kernel<<<NWAVES / 4, 256, 0, stream>>>(si_b, sir_b, sj, sj_r, e, e_r,
                                                rs_j, rs_i, deg_j, deg_i,
                                                recP_j, recP_i, Xb);

  float* out = (float*)d_out;
  gemm_gru_kernel<<<(MTILES + 3) / 4, 512, 0, stream>>>(Xb, Wb, bb, sj_r, sj, out);
  fixup_kernel<<<391, 256, 0, stream>>>(deg_j, deg_i, sj, sj_r, w_hh, b_ih, b_hh, out);
}

// Round 16
// 551.544 us; speedup vs baseline: 1.1579x; 1.0123x over previous
//
#include <hip/hip_runtime.h>
#include <math.h>

#define NUSERS 50000
#define NITEMS 50000
#define NTOT   100000
#define NNODE  50000      // per direction
#define NCHUNK 196        // ceil(50000/256)
#define MTILES 6250       // 100000/16 row tiles
#define KDIM   384        // folded K: [mean_src 128 | tenc 64 | ef 64 | h 128]
#define NWAVES 32768      // gather: 8192 blocks x 4 waves; 4x oversubscribed so
                          // finished blocks retire and queued blocks backfill the tail
#define PBLK   768        // prep: pack_w blocks (512*384/256)
#define CBLK   6250       // prep: cast_mem blocks

typedef __attribute__((ext_vector_type(4))) float f32x4;
typedef __attribute__((ext_vector_type(8))) short short8;
typedef unsigned int u32;

#define AS1 __attribute__((address_space(1)))
#define AS3 __attribute__((address_space(3)))

static __device__ __forceinline__ unsigned short f2bf(float f) {
  unsigned int u = __float_as_uint(f);
  u += 0x7fffu + ((u >> 16) & 1u);
  return (unsigned short)(u >> 16);
}

static __device__ __forceinline__ u32 pack2(float x, float y) {
  return (u32)f2bf(x) | ((u32)f2bf(y) << 16);
}

static __device__ __forceinline__ void gload_lds16(const void* g, void* l) {
  __builtin_amdgcn_global_load_lds((const AS1 u32*)g, (AS3 u32*)l, 16, 0, 0);
}

// ---------------- prep: pack_w + cast_mem + hist fused (independent work) -------
// blocks [0,PBLK): pack W'' (512 gates x 384 k) into MFMA B-fragment order.
//   k<128: W_ih src cols. 128<=k<256: W_ih cols 256:384 (tenc+ef). k>=256 (c):
//     g<256 (rz):   W_ih[g,128+c] + W_hh[g,c]   (dst-mean == h folded)
//     256<=g<384:   W_ih[g,128+c]               (i_n dst part; deg==0 fixed up)
//     g>=384 (h_n): W_hh[g-128,c]
// blocks [PBLK,PBLK+CBLK): bf16 pre-cast of si/si_r (gathered arrays).
// blocks [PBLK+CBLK,...): degree histogram (atomics on zeroed deg arrays).
__global__ void prep_kernel(const float* __restrict__ w_ih,
                            const float* __restrict__ w_hh,
                            const float* __restrict__ b_ih,
                            const float* __restrict__ b_hh,
                            unsigned short* __restrict__ Wb,
                            float* __restrict__ bb,
                            const float* __restrict__ si,
                            const float* __restrict__ si_r,
                            unsigned short* __restrict__ si_b,
                            unsigned short* __restrict__ sir_b,
                            const int* __restrict__ dst_g,
                            const int* __restrict__ dst_gr,
                            int* __restrict__ deg_j, int* __restrict__ deg_i,
                            int E) {
  int blk = blockIdx.x;
  if (blk < PBLK) {
    int idx = blk * 256 + threadIdx.x;              // 0 .. 512*384-1
    int j = idx & 7, l = (idx >> 3) & 63, ktt = idx >> 9;   // ktt = tt*12 + kt
    int kt = ktt % 12, tt = ktt / 12;
    int g = tt * 16 + (l & 15);
    int k = kt * 32 + (l >> 4) * 8 + j;
    float v;
    if (k < 128) {
      v = (g < 384) ? w_ih[g * 384 + k] : 0.0f;
    } else if (k < 256) {
      v = (g < 384) ? w_ih[g * 384 + 128 + k] : 0.0f;   // col 256+(k-128)
    } else {
      int c = k - 256;
      if (g < 256)      v = w_ih[g * 384 + 128 + c] + w_hh[g * 128 + c];
      else if (g < 384) v = w_ih[g * 384 + 128 + c];
      else              v = w_hh[(size_t)(g - 128) * 128 + c];
    }
    Wb[idx] = f2bf(v);
    if (idx < 512) {
      float b = (idx < 256) ? (b_ih[idx] + b_hh[idx])
              : (idx < 384) ? b_ih[idx]
                            : b_hh[idx - 128];
      bb[idx] = b;
    }
  } else if (blk < PBLK + CBLK) {
    int i = (blk - PBLK) * 256 + threadIdx.x;       // 0 .. 1,599,999 (8 floats each)
    const float* src; unsigned short* dst; int off;
    if (i < 800000) { src = si;   dst = si_b;  off = i; }
    else            { src = si_r; dst = sir_b; off = i - 800000; }
    const f32x4* p = (const f32x4*)(src + (size_t)off * 8);
    f32x4 a = p[0], b = p[1];
    short8 o;
    o[0] = f2bf(a[0]); o[1] = f2bf(a[1]); o[2] = f2bf(a[2]); o[3] = f2bf(a[3]);
    o[4] = f2bf(b[0]); o[5] = f2bf(b[1]); o[6] = f2bf(b[2]); o[7] = f2bf(b[3]);
    *(short8*)(dst + (size_t)off * 8) = o;
  } else {
    int i = (blk - PBLK - CBLK) * 256 + threadIdx.x;
    if (i < E) atomicAdd(&deg_j[dst_g[i]], 1);
    else if (i < 2 * E) atomicAdd(&deg_i[dst_gr[i - E]], 1);
  }
}

// ---------------- CSR scan: proven 3-kernel chain (round-12) -----------------
__global__ void chunksum_kernel(const int* __restrict__ deg_j,
                                const int* __restrict__ deg_i,
                                int* __restrict__ csum) {
  int c = blockIdx.x;                    // 0..2*NCHUNK-1
  const int* deg = (c < NCHUNK) ? deg_j : deg_i;
  int cc = (c < NCHUNK) ? c : c - NCHUNK;
  int t = threadIdx.x;
  int idx = cc * 256 + t;
  int v = (idx < NNODE) ? deg[idx] : 0;
  for (int off = 32; off; off >>= 1) v += __shfl_down(v, off, 64);
  __shared__ int wsum[4];
  if ((t & 63) == 0) wsum[t >> 6] = v;
  __syncthreads();
  if (t == 0) csum[c] = wsum[0] + wsum[1] + wsum[2] + wsum[3];
}

__global__ void chunkscan_kernel(const int* __restrict__ csum, int* __restrict__ coff) {
  int d = blockIdx.x;                    // 0 or 1
  const int* cs = csum + d * NCHUNK;
  int* co = coff + d * NCHUNK;
  int t = threadIdx.x, lane = t & 63, w = t >> 6;
  int v = (t < NCHUNK) ? cs[t] : 0;
  int x = v;
  for (int off = 1; off < 64; off <<= 1) {
    int y = __shfl_up(x, off, 64);
    if (lane >= off) x += y;
  }
  __shared__ int wt[4];
  if (lane == 63) wt[w] = x;
  __syncthreads();
  int add = 0;
  for (int k = 0; k < 4; ++k) if (k < w) add += wt[k];
  if (t < NCHUNK) co[t] = add + x - v;   // exclusive prefix
}

__global__ void localscan_kernel(const int* __restrict__ deg_j,
                                 const int* __restrict__ deg_i,
                                 const int* __restrict__ coff,
                                 int* __restrict__ rs_j, int* __restrict__ cur_j,
                                 int* __restrict__ rs_i, int* __restrict__ cur_i) {
  int c = blockIdx.x;
  bool dj = c < NCHUNK;
  const int* deg = dj ? deg_j : deg_i;
  int cc = dj ? c : c - NCHUNK;
  int* rs = dj ? rs_j : rs_i;
  int* cur = dj ? cur_j : cur_i;
  int base = coff[c];
  int t = threadIdx.x, lane = t & 63, w = t >> 6;
  int idx = cc * 256 + t;
  int v = (idx < NNODE) ? deg[idx] : 0;
  int x = v;
  for (int off = 1; off < 64; off <<= 1) {
    int y = __shfl_up(x, off, 64);
    if (lane >= off) x += y;
  }
  __shared__ int wt[4];
  if (lane == 63) wt[w] = x;
  __syncthreads();
  int add = 0;
  for (int k = 0; k < 4; ++k) if (k < w) add += wt[k];
  int ex = base + add + x - v;
  if (idx < NNODE) { rs[idx] = ex; cur[idx] = ex; }
}

// fill: one 16B record per edge: (src, eid, ts_bits, 0)
__global__ void fill_kernel(const int* __restrict__ src_g, const int* __restrict__ dst_g,
                            const float* __restrict__ t,
                            const int* __restrict__ src_gr, const int* __restrict__ dst_gr,
                            const float* __restrict__ t_r,
                            int* __restrict__ cur_j, int* __restrict__ cur_i,
                            int4* __restrict__ recP_j, int4* __restrict__ recP_i,
                            int E) {
  int i = blockIdx.x * 256 + threadIdx.x;
  if (i < E) {
    int pos = atomicAdd(&cur_j[dst_g[i]], 1);
    recP_j[pos] = make_int4(src_g[i], i, __float_as_int(t[i]), 0);
  } else if (i < 2 * E) {
    int k = i - E;
    int pos = atomicAdd(&cur_i[dst_gr[k]], 1);
    recP_i[pos] = make_int4(src_gr[k], k, __float_as_int(t_r[k]), 0);
  }
}

// ---------------- gather: mean-message, write X row NODE-MAJOR (768B) ----------
// packed k layout: [0,128)=mean src_mem, [128,192)=mean tenc, [192,256)=mean ef,
// [256,384)=h. (h*(deg>0) channel folded into packed weights; deg==0 fixed up.)
__global__ __launch_bounds__(256) void gather_kernel(
    const unsigned short* __restrict__ si_b, const unsigned short* __restrict__ sir_b,
    const float* __restrict__ sj, const float* __restrict__ sj_r,
    const float* __restrict__ e, const float* __restrict__ e_r,
    const int* __restrict__ rs_j, const int* __restrict__ rs_i,
    const int* __restrict__ deg_j, const int* __restrict__ deg_i,
    const int4* __restrict__ recP_j, const int4* __restrict__ recP_i,
    unsigned short* __restrict__ Xb) {
  __shared__ __align__(16) unsigned short rowbuf[4][384];
  int wid = threadIdx.x >> 6, lane = threadIdx.x & 63;
  int gwave = blockIdx.x * 4 + wid;                // 0..NWAVES-1
  // freq[lane] = 10^(-9*lane/63) = exp(-lane * 9/63 * ln 10)
  float freq = __expf((float)lane * -0.3289407276f);
  unsigned short* rb = rowbuf[wid];
  u32* rb32 = (u32*)rb;

  for (int node = gwave; node < NTOT; node += NWAVES) {
    bool user = node < NUSERS;
    int idx = user ? node : node - NUSERS;
    const unsigned short* smem = user ? sir_b : si_b;   // bf16 rows, 128 shorts
    const float* h  = user ? sj_r : sj;
    const float* ef = user ? e_r : e;
    int start = __builtin_amdgcn_readfirstlane((user ? rs_i : rs_j)[idx]);
    int deg   = __builtin_amdgcn_readfirstlane((user ? deg_i : deg_j)[idx]);
    const int4* rec = user ? recP_i : recP_j;

    // h row: issue early, consumed only in the epilogue
    float2 hvf = *(const float2*)(h + (size_t)idx * 128 + 2 * lane);

    float asx = 0.f, asy = 0.f;   // mean src_mem, k = 2*lane, 2*lane+1
    float at  = 0.f;              // tenc, k = 128+lane
    float ae  = 0.f;              // edge feat, k = 192+lane

    for (int base = 0; base < deg; base += 64) {
      int nn = deg - base; if (nn > 64) nn = 64;
      // cooperative record load: lane l holds record base+l (clamped)
      int cl = (lane < nn) ? base + lane : base + nn - 1;
      int4 r = rec[start + cl];
      int full = nn & ~7;
      // ---- unclamped full rounds: no weights, no dup loads ----
      for (int j0 = 0; j0 < full; j0 += 8) {
        int s0 = __builtin_amdgcn_readlane(r.x, j0 + 0), e0 = __builtin_amdgcn_readlane(r.y, j0 + 0);
        int s1 = __builtin_amdgcn_readlane(r.x, j0 + 1), e1 = __builtin_amdgcn_readlane(r.y, j0 + 1);
        int s2 = __builtin_amdgcn_readlane(r.x, j0 + 2), e2 = __builtin_amdgcn_readlane(r.y, j0 + 2);
        int s3 = __builtin_amdgcn_readlane(r.x, j0 + 3), e3 = __builtin_amdgcn_readlane(r.y, j0 + 3);
        int s4 = __builtin_amdgcn_readlane(r.x, j0 + 4), e4 = __builtin_amdgcn_readlane(r.y, j0 + 4);
        int s5 = __builtin_amdgcn_readlane(r.x, j0 + 5), e5 = __builtin_amdgcn_readlane(r.y, j0 + 5);
        int s6 = __builtin_amdgcn_readlane(r.x, j0 + 6), e6 = __builtin_amdgcn_readlane(r.y, j0 + 6);
        int s7 = __builtin_amdgcn_readlane(r.x, j0 + 7), e7 = __builtin_amdgcn_readlane(r.y, j0 + 7);

        u32 v0 = *(const u32*)(smem + ((size_t)s0 << 7) + 2 * lane);
        u32 v1 = *(const u32*)(smem + ((size_t)s1 << 7) + 2 * lane);
        u32 v2 = *(const u32*)(smem + ((size_t)s2 << 7) + 2 * lane);
        u32 v3 = *(const u32*)(smem + ((size_t)s3 << 7) + 2 * lane);
        u32 v4 = *(const u32*)(smem + ((size_t)s4 << 7) + 2 * lane);
        u32 v5 = *(const u32*)(smem + ((size_t)s5 << 7) + 2 * lane);
        u32 v6 = *(const u32*)(smem + ((size_t)s6 << 7) + 2 * lane);
        u32 v7 = *(const u32*)(smem + ((size_t)s7 << 7) + 2 * lane);
        float f0 = ef[((size_t)e0 << 6) + lane];
        float f1 = ef[((size_t)e1 << 6) + lane];
        float f2 = ef[((size_t)e2 << 6) + lane];
        float f3 = ef[((size_t)e3 << 6) + lane];
        float f4 = ef[((size_t)e4 << 6) + lane];
        float f5 = ef[((size_t)e5 << 6) + lane];
        float f6 = ef[((size_t)e6 << 6) + lane];
        float f7 = ef[((size_t)e7 << 6) + lane];

        float c0 = __cosf(__int_as_float(__builtin_amdgcn_readlane(r.z, j0 + 0)) * freq);
        float c1 = __cosf(__int_as_float(__builtin_amdgcn_readlane(r.z, j0 + 1)) * freq);
        float c2 = __cosf(__int_as_float(__builtin_amdgcn_readlane(r.z, j0 + 2)) * freq);
        float c3 = __cosf(__int_as_float(__builtin_amdgcn_readlane(r.z, j0 + 3)) * freq);
        float c4 = __cosf(__int_as_float(__builtin_amdgcn_readlane(r.z, j0 + 4)) * freq);
        float c5 = __cosf(__int_as_float(__builtin_amdgcn_readlane(r.z, j0 + 5)) * freq);
        float c6 = __cosf(__int_as_float(__builtin_amdgcn_readlane(r.z, j0 + 6)) * freq);
        float c7 = __cosf(__int_as_float(__builtin_amdgcn_readlane(r.z, j0 + 7)) * freq);

        float l0 = __uint_as_float(v0 << 16), g0 = __uint_as_float(v0 & 0xffff0000u);
        float l1 = __uint_as_float(v1 << 16), g1 = __uint_as_float(v1 & 0xffff0000u);
        float l2 = __uint_as_float(v2 << 16), g2 = __uint_as_float(v2 & 0xffff0000u);
        float l3 = __uint_as_float(v3 << 16), g3 = __uint_as_float(v3 & 0xffff0000u);
        float l4 = __uint_as_float(v4 << 16), g4 = __uint_as_float(v4 & 0xffff0000u);
        float l5 = __uint_as_float(v5 << 16), g5 = __uint_as_float(v5 & 0xffff0000u);
        float l6 = __uint_as_float(v6 << 16), g6 = __uint_as_float(v6 & 0xffff0000u);
        float l7 = __uint_as_float(v7 << 16), g7 = __uint_as_float(v7 & 0xffff0000u);

        asx += ((l0 + l1) + (l2 + l3)) + ((l4 + l5) + (l6 + l7));
        asy += ((g0 + g1) + (g2 + g3)) + ((g4 + g5) + (g6 + g7));
        at  += ((c0 + c1) + (c2 + c3)) + ((c4 + c5) + (c6 + c7));
        ae  += ((f0 + f1) + (f2 + f3)) + ((f4 + f5) + (f6 + f7));
      }
      // ---- clamped tail (1..7 real edges) ----
      if (full < nn) {
        int j0 = full;
        int j1 = (j0 + 1 < nn) ? j0 + 1 : nn - 1;
        int j2 = (j0 + 2 < nn) ? j0 + 2 : nn - 1;
        int j3 = (j0 + 3 < nn) ? j0 + 3 : nn - 1;
        int j4 = (j0 + 4 < nn) ? j0 + 4 : nn - 1;
        int j5 = (j0 + 5 < nn) ? j0 + 5 : nn - 1;
        int j6 = (j0 + 6 < nn) ? j0 + 6 : nn - 1;
        float w1 = (j0 + 1 < nn) ? 1.0f : 0.0f;
        float w2 = (j0 + 2 < nn) ? 1.0f : 0.0f;
        float w3 = (j0 + 3 < nn) ? 1.0f : 0.0f;
        float w4 = (j0 + 4 < nn) ? 1.0f : 0.0f;
        float w5 = (j0 + 5 < nn) ? 1.0f : 0.0f;
        float w6 = (j0 + 6 < nn) ? 1.0f : 0.0f;

        int s0 = __builtin_amdgcn_readlane(r.x, j0), e0 = __builtin_amdgcn_readlane(r.y, j0);
        int s1 = __builtin_amdgcn_readlane(r.x, j1), e1 = __builtin_amdgcn_readlane(r.y, j1);
        int s2 = __builtin_amdgcn_readlane(r.x, j2), e2 = __builtin_amdgcn_readlane(r.y, j2);
        int s3 = __builtin_amdgcn_readlane(r.x, j3), e3 = __builtin_amdgcn_readlane(r.y, j3);
        int s4 = __builtin_amdgcn_readlane(r.x, j4), e4 = __builtin_amdgcn_readlane(r.y, j4);
        int s5 = __builtin_amdgcn_readlane(r.x, j5), e5 = __builtin_amdgcn_readlane(r.y, j5);
        int s6 = __builtin_amdgcn_readlane(r.x, j6), e6 = __builtin_amdgcn_readlane(r.y, j6);

        u32 v0 = *(const u32*)(smem + ((size_t)s0 << 7) + 2 * lane);
        u32 v1 = *(const u32*)(smem + ((size_t)s1 << 7) + 2 * lane);
        u32 v2 = *(const u32*)(smem + ((size_t)s2 << 7) + 2 * lane);
        u32 v3 = *(const u32*)(smem + ((size_t)s3 << 7) + 2 * lane);
        u32 v4 = *(const u32*)(smem + ((size_t)s4 << 7) + 2 * lane);
        u32 v5 = *(const u32*)(smem + ((size_t)s5 << 7) + 2 * lane);
        u32 v6 = *(const u32*)(smem + ((size_t)s6 << 7) + 2 * lane);
        float f0 = ef[((size_t)e0 << 6) + lane];
        float f1 = ef[((size_t)e1 << 6) + lane];
        float f2 = ef[((size_t)e2 << 6) + lane];
        float f3 = ef[((size_t)e3 << 6) + lane];
        float f4 = ef[((size_t)e4 << 6) + lane];
        float f5 = ef[((size_t)e5 << 6) + lane];
        float f6 = ef[((size_t)e6 << 6) + lane];

        float c0 = __cosf(__int_as_float(__builtin_amdgcn_readlane(r.z, j0)) * freq);
        float c1 = __cosf(__int_as_float(__builtin_amdgcn_readlane(r.z, j1)) * freq);
        float c2 = __cosf(__int_as_float(__builtin_amdgcn_readlane(r.z, j2)) * freq);
        float c3 = __cosf(__int_as_float(__builtin_amdgcn_readlane(r.z, j3)) * freq);
        float c4 = __cosf(__int_as_float(__builtin_amdgcn_readlane(r.z, j4)) * freq);
        float c5 = __cosf(__int_as_float(__builtin_amdgcn_readlane(r.z, j5)) * freq);
        float c6 = __cosf(__int_as_float(__builtin_amdgcn_readlane(r.z, j6)) * freq);

        float l0 = __uint_as_float(v0 << 16), g0 = __uint_as_float(v0 & 0xffff0000u);
        float l1 = __uint_as_float(v1 << 16), g1 = __uint_as_float(v1 & 0xffff0000u);
        float l2 = __uint_as_float(v2 << 16), g2 = __uint_as_float(v2 & 0xffff0000u);
        float l3 = __uint_as_float(v3 << 16), g3 = __uint_as_float(v3 & 0xffff0000u);
        float l4 = __uint_as_float(v4 << 16), g4 = __uint_as_float(v4 & 0xffff0000u);
        float l5 = __uint_as_float(v5 << 16), g5 = __uint_as_float(v5 & 0xffff0000u);
        float l6 = __uint_as_float(v6 << 16), g6 = __uint_as_float(v6 & 0xffff0000u);

        asx += l0 + w1 * l1 + w2 * l2 + w3 * l3 + w4 * l4 + w5 * l5 + w6 * l6;
        asy += g0 + w1 * g1 + w2 * g2 + w3 * g3 + w4 * g4 + w5 * g5 + w6 * g6;
        at  += c0 + w1 * c1 + w2 * c2 + w3 * c3 + w4 * c4 + w5 * c5 + w6 * c6;
        ae  += f0 + w1 * f1 + w2 * f2 + w3 * f3 + w4 * f4 + w5 * f5 + w6 * f6;
      }
    }

    float invc = (deg > 0) ? 1.0f / (float)deg : 0.0f;

    rb32[lane]       = pack2(asx * invc, asy * invc);   // k = 2*lane,2*lane+1
    rb[128 + lane]   = f2bf(at * invc);                 // k = 128+lane
    rb[192 + lane]   = f2bf(ae * invc);                 // k = 192+lane
    rb32[128 + lane] = pack2(hvf.x, hvf.y);             // k = 256+2*lane

    // wave-private LDS transpose, then node-major row write (768B contiguous)
    if (lane < 48) {
      short8 vv = *(const short8*)(rb + lane * 8);
      *(short8*)(Xb + (size_t)node * KDIM + lane * 8) = vv;
    }
  }
}

// ---------------- GEMM (100000 x 384) @ W''^T with fused GRU epilogue ----------------
// v12 structure (two barrier domains/CU) at K=384 (12 kt steps). Block = 512 thr /
// 8 waves, tile 4 mtiles x 512 out-cols. LDS = sA 2x4KB + sW 2x32KB = 72KB -> 2
// blocks/CU. Wave = 2 mtiles x 128 cols, ~125 VGPR.
__global__ __launch_bounds__(512, 4) void gemm_gru_kernel(
    const unsigned short* __restrict__ Xb,
    const unsigned short* __restrict__ Wb,
    const float* __restrict__ bb,
    const float* __restrict__ sj_r,
    const float* __restrict__ sj,
    float* __restrict__ out) {
  __shared__ __align__(16) unsigned short sA[2][2048];    // 2 x 4 KB : [mt4][512]
  __shared__ __align__(16) unsigned short sW[2][16384];   // 2 x 32 KB: [tt32][512]
  int wid = threadIdx.x >> 6, lane = threadIdx.x & 63;
  int mg = wid >> 2, cg = wid & 3;         // m-group 0..1, col-group 0..3
  int mbase = blockIdx.x * 4;
  int col16 = lane & 15, quad = lane >> 4;

  // staging sources: wave wid stages W slices tt = wid*4..wid*4+3;
  // waves 0..3 additionally stage A slice mt4 = wid.
  int mts = mbase + (wid & 3); if (mts >= MTILES) mts = MTILES - 1;
  const unsigned short* gA = Xb + (size_t)(mts * 16 + col16) * KDIM + quad * 8;
  const unsigned short* gB = Wb + (size_t)(wid * 4) * 12 * 512 + lane * 8;

#define STG(buf, kt)                                                          \
  {                                                                           \
    _Pragma("unroll")                                                         \
    for (int i = 0; i < 4; ++i)                                               \
      gload_lds16(gB + ((size_t)(i * 12 + (kt))) * 512, sW[buf] + (wid * 4 + i) * 512); \
    if (wid < 4) gload_lds16(gA + (kt) * 32, sA[buf] + (wid & 3) * 512);      \
  }

  f32x4 acc[2][8];                         // [mi][g*2+nt]
#pragma unroll
  for (int mi = 0; mi < 2; ++mi)
#pragma unroll
    for (int t8 = 0; t8 < 8; ++t8) acc[mi][t8] = (f32x4)0.0f;

  STG(0, 0)
  __syncthreads();

  for (int kt = 0; kt < 12; ++kt) {
    int cur = kt & 1;
    if (kt < 11) STG(cur ^ 1, kt + 1)
    short8 a[2], b[8];
#pragma unroll
    for (int mi = 0; mi < 2; ++mi)
      a[mi] = *(const short8*)(sA[cur] + (mg * 2 + mi) * 512 + lane * 8);
#pragma unroll
    for (int g = 0; g < 4; ++g)
#pragma unroll
      for (int nt = 0; nt < 2; ++nt)
        b[g * 2 + nt] = *(const short8*)(sW[cur] + (g * 8 + cg * 2 + nt) * 512 + lane * 8);
#pragma unroll
    for (int mi = 0; mi < 2; ++mi)
#pragma unroll
      for (int t8 = 0; t8 < 8; ++t8)
        acc[mi][t8] = __builtin_amdgcn_mfma_f32_16x16x32_bf16(a[mi], b[t8], acc[mi][t8], 0, 0, 0);
    __syncthreads();
  }

  // fused GRU epilogue: wave owns out cols (cg*2+nt)*16+col16, rows = its 2 mtiles
#pragma unroll
  for (int nt = 0; nt < 2; ++nt) {
    int cc = (cg * 2 + nt) * 16 + col16;
    float bbr = bb[cc], bbz = bb[128 + cc], bbn = bb[256 + cc], bbh = bb[384 + cc];
#pragma unroll
    for (int mi = 0; mi < 2; ++mi) {
      int mt = mbase + mg * 2 + mi;
      if (mt >= MTILES) continue;
#pragma unroll
      for (int r = 0; r < 4; ++r) {
        int row = mt * 16 + quad * 4 + r;
        float rp  = acc[mi][0 + nt][r] + bbr;   // gate r: t8 = 0*2+nt
        float zp  = acc[mi][2 + nt][r] + bbz;   // gate z: t8 = 1*2+nt
        float inp = acc[mi][4 + nt][r] + bbn;   // gate n: t8 = 2*2+nt
        float hnp = acc[mi][6 + nt][r] + bbh;   // gate h: t8 = 3*2+nt
        float rg = 1.0f / (1.0f + __expf(-rp));
        float zg = 1.0f / (1.0f + __expf(-zp));
        float ng = tanhf(inp + rg * hnp);
        float hv = (row < NUSERS) ? sj_r[(size_t)row * 128 + cc]
                                  : sj[(size_t)(row - NUSERS) * 128 + cc];
        out[(size_t)row * 128 + cc] = (1.0f - zg) * ng + zg * hv;
      }
    }
  }
}

// ---------------- fixup: deg==0 nodes (weight fold invalid there) --------------
// For deg==0: x = 0 -> gi = b_ih; gh = h@W_hh^T + b_hh. ~34 nodes expected.
__global__ __launch_bounds__(256) void fixup_kernel(
    const int* __restrict__ deg_j, const int* __restrict__ deg_i,
    const float* __restrict__ sj, const float* __restrict__ sj_r,
    const float* __restrict__ w_hh, const float* __restrict__ b_ih,
    const float* __restrict__ b_hh, float* __restrict__ out) {
  int w = blockIdx.x * 4 + (threadIdx.x >> 6), lane = threadIdx.x & 63;
  long base = (long)w * 64;
  if (base >= NTOT) return;
  int node = (int)base + lane;
  int dg = 1;
  if (node < NTOT) {
    bool user = node < NUSERS;
    dg = user ? deg_i[node] : deg_j[node - NUSERS];
  }
  unsigned long long zm = __ballot(dg == 0);
  while (zm) {
    int b = __ffsll((long long)zm) - 1; zm &= zm - 1;
    int zn = (int)base + b;
    bool zu = zn < NUSERS;
    const float* h = zu ? (sj_r + (size_t)zn * 128) : (sj + (size_t)(zn - NUSERS) * 128);
#pragma unroll
    for (int half = 0; half < 2; ++half) {
      int c = half * 64 + lane;
      float gr = 0.f, gz = 0.f, gn = 0.f;
      for (int k = 0; k < 128; ++k) {
        float hk = h[k];
        gr += w_hh[(size_t)c * 128 + k] * hk;
        gz += w_hh[(size_t)(128 + c) * 128 + k] * hk;
        gn += w_hh[(size_t)(256 + c) * 128 + k] * hk;
      }
      float rg = 1.0f / (1.0f + __expf(-(b_ih[c] + b_hh[c] + gr)));
      float zg = 1.0f / (1.0f + __expf(-(b_ih[128 + c] + b_hh[128 + c] + gz)));
      float ng = tanhf(b_ih[256 + c] + rg * (b_hh[256 + c] + gn));
      out[(size_t)zn * 128 + c] = (1.0f - zg) * ng + zg * h[c];
    }
  }
}

extern "C" void kernel_launch(void* const* d_in, const int* in_sizes, int n_in,
                              void* d_out, int out_size, void* d_ws, size_t ws_size,
                              hipStream_t stream) {
  const float* si   = (const float*)d_in[0];
  const float* sj   = (const float*)d_in[1];
  const float* si_r = (const float*)d_in[2];
  const float* sj_r = (const float*)d_in[3];
  const float* t    = (const float*)d_in[4];
  const float* t_r  = (const float*)d_in[5];
  const float* e    = (const float*)d_in[6];
  const float* e_r  = (const float*)d_in[7];
  const float* w_ih = (const float*)d_in[8];
  const float* w_hh = (const float*)d_in[9];
  const float* b_ih = (const float*)d_in[10];
  const float* b_hh = (const float*)d_in[11];
  const int* src_g  = (const int*)d_in[12];
  const int* dst_g  = (const int*)d_in[13];
  const int* src_gr = (const int*)d_in[14];
  const int* dst_gr = (const int*)d_in[15];
  int E = in_sizes[4];

  // workspace layout (16B-aligned head first)
  unsigned short* Xb = (unsigned short*)d_ws;          // NTOT*384 shorts (76.8 MB), node-major
  unsigned short* Wb = Xb + (size_t)NTOT * KDIM;       // 512*384 = 196608 shorts
  float* bb   = (float*)(Wb + 196608);                 // 512
  int* deg_j  = (int*)(bb + 512);                      // 50000  (memset target, with deg_i)
  int* deg_i  = deg_j + NNODE;                         // 50000
  int* rs_j   = deg_i + NNODE;                         // 50000
  int* rs_i   = rs_j + NNODE;                          // 50000
  int* cur_j  = rs_i + NNODE;                          // 50000
  int* cur_i  = cur_j + NNODE;                         // 50000
  int* csum   = cur_i + NNODE;                         // 2*NCHUNK
  int* coff   = csum + 2 * NCHUNK;                     // 2*NCHUNK (ends 16B-aligned)
  int4* recP_j = (int4*)(coff + 2 * NCHUNK);           // E int4
  int4* recP_i = recP_j + E;                           // E int4
  unsigned short* si_b  = (unsigned short*)(recP_i + E);  // 6.4M shorts (12.8 MB)
  unsigned short* sir_b = si_b + 6400000;                 // 6.4M shorts (12.8 MB)

  hipMemsetAsync(deg_j, 0, 2 * NNODE * sizeof(int), stream);

  int hblks = (2 * E + 255) / 256;
  prep_kernel<<<PBLK + CBLK + hblks, 256, 0, stream>>>(
      w_ih, w_hh, b_ih, b_hh, Wb, bb,
      si, si_r, si_b, sir_b,
      dst_g, dst_gr, deg_j, deg_i, E);

  chunksum_kernel<<<2 * NCHUNK, 256, 0, stream>>>(deg_j, deg_i, csum);
  chunkscan_kernel<<<2, 256, 0, stream>>>(csum, coff);
  localscan_kernel<<<2 * NCHUNK, 256, 0, stream>>>(deg_j, deg_i, coff, rs_j, cur_j, rs_i, cur_i);

  fill_kernel<<<hblks, 256, 0, stream>>>(src_g, dst_g, t, src_gr, dst_gr, t_r,
                                         cur_j, cur_i, recP_j, recP_i, E);

  gather_kernel<<<NWAVES / 4, 256, 0, stream>>>(si_b, sir_b, sj, sj_r, e, e_r,
                                                rs_j, rs_i, deg_j, deg_i,
                                                recP_j, recP_i, Xb);

  float* out = (float*)d_out;
  gemm_gru_kernel<<<(MTILES + 3) / 4, 512, 0, stream>>>(Xb, Wb, bb, sj_r, sj, out);
  fixup_kernel<<<391, 256, 0, stream>>>(deg_j, deg_i, sj, sj_r, w_hh, b_ih, b_hh, out);
}